// Round 2
// baseline (8061.559 us; speedup 1.0000x reference)
//
#include <hip/hip_runtime.h>
#include <hip/hip_bf16.h>

#define BB 2
#define SS 2048
#define DD 1024
#define HH 16
#define DKK 64
// M = BB*SS = 4096, N = K = DD = 1024

// C = A @ W^T + bias.  A: [M, KD] row-major fp32, W: [N, KD] row-major fp32,
// bias: [N] fp32.
// SCATTER=true : write fp32 into [B,H,S,DK] layout
// SCATTER=false: write fp32 into [M,N] layout
template <bool SCATTER>
__global__ __launch_bounds__(256) void gemm_bias(const float* __restrict__ A,
                                                 const float* __restrict__ W,
                                                 const float* __restrict__ bias,
                                                 float* __restrict__ out) {
    const int N = DD, KD = DD;
    __shared__ float As[16][65];  // [k][m]
    __shared__ float Bs[16][65];  // [k][n]
    int t = threadIdx.x;
    int m0 = blockIdx.y * 64;
    int n0 = blockIdx.x * 64;
    int lr = t >> 4;   // 0..15
    int lc = t & 15;   // 0..15
    int ty = t >> 4;   // 0..15
    int tx = t & 15;   // 0..15
    float acc[4][4] = {};

    for (int k0 = 0; k0 < KD; k0 += 16) {
#pragma unroll
        for (int c = 0; c < 4; ++c) {
            int row = lr + c * 16;
            As[lc][row] = A[(size_t)(m0 + row) * KD + k0 + lc];
            Bs[lc][row] = W[(size_t)(n0 + row) * KD + k0 + lc];
        }
        __syncthreads();
#pragma unroll
        for (int kk = 0; kk < 16; ++kk) {
            float a[4], b[4];
#pragma unroll
            for (int i = 0; i < 4; ++i) a[i] = As[kk][ty + 16 * i];
#pragma unroll
            for (int j = 0; j < 4; ++j) b[j] = Bs[kk][tx + 16 * j];
#pragma unroll
            for (int i = 0; i < 4; ++i)
#pragma unroll
                for (int j = 0; j < 4; ++j) acc[i][j] += a[i] * b[j];
        }
        __syncthreads();
    }

#pragma unroll
    for (int i = 0; i < 4; ++i) {
        int m = m0 + ty + 16 * i;
#pragma unroll
        for (int j = 0; j < 4; ++j) {
            int n = n0 + tx + 16 * j;
            float val = acc[i][j] + bias[n];
            if (SCATTER) {
                int b_ = m / SS, s_ = m % SS;
                int h_ = n / DKK, d_ = n % DKK;
                out[(((size_t)b_ * HH + h_) * SS + s_) * DKK + d_] = val;
            } else {
                out[(size_t)m * N + n] = val;
            }
        }
    }
}

// One block (256 threads) per (b,h,q).  Q,K,V: fp32 [B,H,S,DK].
// Writes context directly in concat layout [B,S,D] fp32.
__global__ __launch_bounds__(256) void attn_kernel(const float* __restrict__ Q,
                                                   const float* __restrict__ K,
                                                   const float* __restrict__ V,
                                                   const int* __restrict__ mask,
                                                   float* __restrict__ C) {
    int bhq = blockIdx.x;
    int qi = bhq % SS;
    int bh = bhq / SS;  // b*H + h
    int h = bh % HH;
    int b = bh / HH;
    const float* Qrow = Q + (size_t)bhq * DKK;
    const float* Kb = K + (size_t)bh * SS * DKK;
    const float* Vb = V + (size_t)bh * SS * DKK;
    int t = threadIdx.x;

    __shared__ float qrow[DKK];
    __shared__ float sc[SS];
    __shared__ float red[256];
    __shared__ float part[4][DKK];

    if (t < DKK) qrow[t] = Qrow[t];
    __syncthreads();

    // scores + local max
    float lmax = -1e30f;
    for (int kk = t; kk < SS; kk += 256) {
        const float* Kr = Kb + (size_t)kk * DKK;
        float dot = 0.f;
#pragma unroll
        for (int d = 0; d < DKK; ++d) dot += qrow[d] * Kr[d];
        dot *= 0.125f;  // 1/sqrt(64)
        if (mask[(size_t)qi * SS + kk] == 0) dot = -1e9f;
        sc[kk] = dot;
        lmax = fmaxf(lmax, dot);
    }
    red[t] = lmax;
    __syncthreads();
    for (int s2 = 128; s2 > 0; s2 >>= 1) {
        if (t < s2) red[t] = fmaxf(red[t], red[t + s2]);
        __syncthreads();
    }
    float smax = red[0];
    __syncthreads();

    // exp + local sum
    float lsum = 0.f;
    for (int kk = t; kk < SS; kk += 256) {
        float p = __expf(sc[kk] - smax);
        sc[kk] = p;
        lsum += p;
    }
    red[t] = lsum;
    __syncthreads();
    for (int s2 = 128; s2 > 0; s2 >>= 1) {
        if (t < s2) red[t] += red[t + s2];
        __syncthreads();
    }
    float inv = 1.f / red[0];
    __syncthreads();

    // context: 4 key-groups x 64 dims
    int g = t >> 6;
    int d = t & 63;
    float acc = 0.f;
    for (int kk = g; kk < SS; kk += 4) {
        acc += sc[kk] * Vb[(size_t)kk * DKK + d];
    }
    part[g][d] = acc;
    __syncthreads();
    if (t < DKK) {
        float ctx = (part[0][t] + part[1][t] + part[2][t] + part[3][t]) * inv;
        C[((size_t)b * SS + qi) * DD + h * DKK + t] = ctx;
    }
}

extern "C" void kernel_launch(void* const* d_in, const int* in_sizes, int n_in,
                              void* d_out, int out_size, void* d_ws, size_t ws_size,
                              hipStream_t stream) {
    const float* q = (const float*)d_in[0];
    const float* k = (const float*)d_in[1];
    const float* v = (const float*)d_in[2];
    const int* mask = (const int*)d_in[3];
    const float* Wq = (const float*)d_in[4];
    const float* bq = (const float*)d_in[5];
    const float* Wk = (const float*)d_in[6];
    const float* bk = (const float*)d_in[7];
    const float* Wv = (const float*)d_in[8];
    const float* bv = (const float*)d_in[9];
    const float* Wo = (const float*)d_in[10];
    const float* bo = (const float*)d_in[11];
    float* out = (float*)d_out;

    const size_t NELEM = (size_t)BB * SS * DD;  // 4M
    float* Qf = (float*)d_ws;
    float* Kf = Qf + NELEM;
    float* Vf = Kf + NELEM;
    float* Cf = Vf + NELEM;

    dim3 grid(DD / 64, (BB * SS) / 64);  // 16 x 64
    gemm_bias<true><<<grid, 256, 0, stream>>>(q, Wq, bq, Qf);
    gemm_bias<true><<<grid, 256, 0, stream>>>(k, Wk, bk, Kf);
    gemm_bias<true><<<grid, 256, 0, stream>>>(v, Wv, bv, Vf);

    attn_kernel<<<BB * HH * SS, 256, 0, stream>>>(Qf, Kf, Vf, mask, Cf);

    gemm_bias<false><<<grid, 256, 0, stream>>>(Cf, Wo, bo, out);
}

// Round 3
// 946.239 us; speedup vs baseline: 8.5196x; 8.5196x over previous
//
#include <hip/hip_runtime.h>
#include <hip/hip_bf16.h>

#define BB 2
#define SS 2048
#define DD 1024
#define HH 16
#define DKK 64
// M = BB*SS = 4096, N = K = DD = 1024

typedef __hip_bfloat16 bf16;
using frag_ab = __attribute__((ext_vector_type(8))) short;  // 8 bf16 (4 VGPRs)
using frag_cd = __attribute__((ext_vector_type(4))) float;  // 4 fp32

__device__ inline unsigned short f2bf(float f) {
    bf16 h = __float2bfloat16(f);
    return *reinterpret_cast<unsigned short*>(&h);
}

// ---------------- projection / output GEMMs (unchanged from R2) ----------------
template <bool SCATTER>
__global__ __launch_bounds__(256) void gemm_bias(const float* __restrict__ A,
                                                 const float* __restrict__ W,
                                                 const float* __restrict__ bias,
                                                 float* __restrict__ out) {
    const int N = DD, KD = DD;
    __shared__ float As[16][65];
    __shared__ float Bs[16][65];
    int t = threadIdx.x;
    int m0 = blockIdx.y * 64;
    int n0 = blockIdx.x * 64;
    int lr = t >> 4;
    int lc = t & 15;
    int ty = t >> 4;
    int tx = t & 15;
    float acc[4][4] = {};

    for (int k0 = 0; k0 < KD; k0 += 16) {
#pragma unroll
        for (int c = 0; c < 4; ++c) {
            int row = lr + c * 16;
            As[lc][row] = A[(size_t)(m0 + row) * KD + k0 + lc];
            Bs[lc][row] = W[(size_t)(n0 + row) * KD + k0 + lc];
        }
        __syncthreads();
#pragma unroll
        for (int kk = 0; kk < 16; ++kk) {
            float a[4], b[4];
#pragma unroll
            for (int i = 0; i < 4; ++i) a[i] = As[kk][ty + 16 * i];
#pragma unroll
            for (int j = 0; j < 4; ++j) b[j] = Bs[kk][tx + 16 * j];
#pragma unroll
            for (int i = 0; i < 4; ++i)
#pragma unroll
                for (int j = 0; j < 4; ++j) acc[i][j] += a[i] * b[j];
        }
        __syncthreads();
    }

#pragma unroll
    for (int i = 0; i < 4; ++i) {
        int m = m0 + ty + 16 * i;
#pragma unroll
        for (int j = 0; j < 4; ++j) {
            int n = n0 + tx + 16 * j;
            float val = acc[i][j] + bias[n];
            if (SCATTER) {
                int b_ = m / SS, s_ = m % SS;
                int h_ = n / DKK, d_ = n % DKK;
                out[(((size_t)b_ * HH + h_) * SS + s_) * DKK + d_] = val;
            } else {
                out[(size_t)m * N + n] = val;
            }
        }
    }
}

// ---------------- flash attention with bf16 MFMA ----------------
// Grid: B*H*(S/64) blocks, 256 threads (4 waves). Wave w owns Q rows w*16..+15
// of this block's 64-query tile. Loops over 32 K-tiles of 64 keys.
__global__ __launch_bounds__(256) void attn_mfma(const float* __restrict__ Q,
                                                 const float* __restrict__ K,
                                                 const float* __restrict__ V,
                                                 const int* __restrict__ mask,
                                                 float* __restrict__ C) {
    __shared__ unsigned short Qs[64][72];   // [q][d] bf16, pre-scaled by 1/8
    __shared__ unsigned short Ks[64][72];   // [key][d] bf16
    __shared__ unsigned short Vt[64][72];   // [d][key] bf16 (transposed)
    __shared__ unsigned short Pw[4][16][72];// per-wave P scratch [qrow][key]

    int blk = blockIdx.x;
    int qt = blk & 31;          // q-tile index
    int bh = blk >> 5;          // b*H + h
    int h = bh & 15;
    int b = bh >> 4;
    int q0 = qt * 64;

    const float* Qg = Q + ((size_t)bh * SS + q0) * DKK;
    const float* Kb = K + (size_t)bh * SS * DKK;
    const float* Vb = V + (size_t)bh * SS * DKK;

    int t = threadIdx.x;
    int w = t >> 6;             // wave 0..3
    int lane = t & 63;
    int quad = lane >> 4;       // 0..3
    int l16 = lane & 15;        // 0..15

    // ---- stage Q tile (scaled by 1/sqrt(DK)=0.125) ----
    {
        int row = t >> 2;           // 0..63
        int d0 = (t & 3) * 16;
#pragma unroll
        for (int i = 0; i < 4; ++i) {
            float4 v4 = *(const float4*)&Qg[(size_t)row * DKK + d0 + 4 * i];
            ushort4 u;
            u.x = f2bf(v4.x * 0.125f); u.y = f2bf(v4.y * 0.125f);
            u.z = f2bf(v4.z * 0.125f); u.w = f2bf(v4.w * 0.125f);
            *(ushort4*)&Qs[row][d0 + 4 * i] = u;
        }
    }
    __syncthreads();

    // loop-invariant Q A-frags: A[m=l16][k=quad*8+j]
    int qrow = w * 16 + l16;
    frag_ab aq0 = *(const frag_ab*)&Qs[qrow][quad * 8];
    frag_ab aq1 = *(const frag_ab*)&Qs[qrow][32 + quad * 8];

    frag_cd o[4];
#pragma unroll
    for (int dt = 0; dt < 4; ++dt) o[dt] = frag_cd{0.f, 0.f, 0.f, 0.f};
    float m_prev[4] = {-1e30f, -1e30f, -1e30f, -1e30f};
    float l_run[4] = {0.f, 0.f, 0.f, 0.f};

    for (int kt = 0; kt < 32; ++kt) {
        __syncthreads();  // previous iteration's reads done before re-staging
        // ---- stage K tile (row-major) and V tile (transposed) ----
        {
            int row = t >> 2;
            int d0 = (t & 3) * 16;
            const float* Kr = Kb + ((size_t)(kt * 64 + row)) * DKK + d0;
            const float* Vr = Vb + ((size_t)(kt * 64 + row)) * DKK + d0;
#pragma unroll
            for (int i = 0; i < 4; ++i) {
                float4 kv = *(const float4*)&Kr[4 * i];
                ushort4 u;
                u.x = f2bf(kv.x); u.y = f2bf(kv.y); u.z = f2bf(kv.z); u.w = f2bf(kv.w);
                *(ushort4*)&Ks[row][d0 + 4 * i] = u;
                float4 vv = *(const float4*)&Vr[4 * i];
                Vt[d0 + 4 * i + 0][row] = f2bf(vv.x);
                Vt[d0 + 4 * i + 1][row] = f2bf(vv.y);
                Vt[d0 + 4 * i + 2][row] = f2bf(vv.z);
                Vt[d0 + 4 * i + 3][row] = f2bf(vv.w);
            }
        }
        __syncthreads();

        // ---- scores S = Q·K^T for this wave's 16 rows x 64 keys ----
        float s[4][4];  // [nt][reg]
#pragma unroll
        for (int nt = 0; nt < 4; ++nt) {
            frag_ab bk0 = *(const frag_ab*)&Ks[nt * 16 + l16][quad * 8];
            frag_ab bk1 = *(const frag_ab*)&Ks[nt * 16 + l16][32 + quad * 8];
            frag_cd sf = frag_cd{0.f, 0.f, 0.f, 0.f};
            sf = __builtin_amdgcn_mfma_f32_16x16x32_bf16(aq0, bk0, sf, 0, 0, 0);
            sf = __builtin_amdgcn_mfma_f32_16x16x32_bf16(aq1, bk1, sf, 0, 0, 0);
#pragma unroll
            for (int r = 0; r < 4; ++r) s[nt][r] = sf[r];
        }

        // ---- mask: element (nt, reg) is (q = w*16+quad*4+reg, k = kt*64+nt*16+l16)
#pragma unroll
        for (int nt = 0; nt < 4; ++nt) {
            int kg = kt * 64 + nt * 16 + l16;
#pragma unroll
            for (int r = 0; r < 4; ++r) {
                int qg = q0 + w * 16 + quad * 4 + r;
                if (mask[(size_t)qg * SS + kg] == 0) s[nt][r] = -1e9f;
            }
        }

        // ---- online softmax (rows live in quad lanes; width-16 butterflies) ----
        float mnew[4], alpha[4], rsum[4];
#pragma unroll
        for (int r = 0; r < 4; ++r) {
            float mc = fmaxf(fmaxf(s[0][r], s[1][r]), fmaxf(s[2][r], s[3][r]));
#pragma unroll
            for (int d = 1; d < 16; d <<= 1) mc = fmaxf(mc, __shfl_xor(mc, d));
            mnew[r] = fmaxf(m_prev[r], mc);
            alpha[r] = __expf(m_prev[r] - mnew[r]);
        }
        float p[4][4];
#pragma unroll
        for (int r = 0; r < 4; ++r) {
            float ls = 0.f;
#pragma unroll
            for (int nt = 0; nt < 4; ++nt) {
                p[nt][r] = __expf(s[nt][r] - mnew[r]);
                ls += p[nt][r];
            }
#pragma unroll
            for (int d = 1; d < 16; d <<= 1) ls += __shfl_xor(ls, d);
            l_run[r] = l_run[r] * alpha[r] + ls;
            m_prev[r] = mnew[r];
        }
#pragma unroll
        for (int dt = 0; dt < 4; ++dt)
#pragma unroll
            for (int r = 0; r < 4; ++r) o[dt][r] *= alpha[r];

        // ---- P: C-layout -> A-layout via wave-private LDS round-trip ----
#pragma unroll
        for (int nt = 0; nt < 4; ++nt)
#pragma unroll
            for (int r = 0; r < 4; ++r)
                Pw[w][quad * 4 + r][nt * 16 + l16] = f2bf(p[nt][r]);

        frag_ab ap0 = *(const frag_ab*)&Pw[w][l16][quad * 8];
        frag_ab ap1 = *(const frag_ab*)&Pw[w][l16][32 + quad * 8];

        // ---- O += P·V ----
#pragma unroll
        for (int dt = 0; dt < 4; ++dt) {
            frag_ab bv0 = *(const frag_ab*)&Vt[dt * 16 + l16][quad * 8];
            frag_ab bv1 = *(const frag_ab*)&Vt[dt * 16 + l16][32 + quad * 8];
            o[dt] = __builtin_amdgcn_mfma_f32_16x16x32_bf16(ap0, bv0, o[dt], 0, 0, 0);
            o[dt] = __builtin_amdgcn_mfma_f32_16x16x32_bf16(ap1, bv1, o[dt], 0, 0, 0);
        }
    }

    // ---- epilogue: normalize and write concat layout [B,S,D] fp32 ----
    float inv[4];
#pragma unroll
    for (int r = 0; r < 4; ++r) inv[r] = 1.f / l_run[r];
#pragma unroll
    for (int dt = 0; dt < 4; ++dt) {
#pragma unroll
        for (int r = 0; r < 4; ++r) {
            int qg = q0 + w * 16 + quad * 4 + r;
            C[((size_t)b * SS + qg) * DD + h * 64 + dt * 16 + l16] = o[dt][r] * inv[r];
        }
    }
}

extern "C" void kernel_launch(void* const* d_in, const int* in_sizes, int n_in,
                              void* d_out, int out_size, void* d_ws, size_t ws_size,
                              hipStream_t stream) {
    const float* q = (const float*)d_in[0];
    const float* k = (const float*)d_in[1];
    const float* v = (const float*)d_in[2];
    const int* mask = (const int*)d_in[3];
    const float* Wq = (const float*)d_in[4];
    const float* bq = (const float*)d_in[5];
    const float* Wk = (const float*)d_in[6];
    const float* bk = (const float*)d_in[7];
    const float* Wv = (const float*)d_in[8];
    const float* bv = (const float*)d_in[9];
    const float* Wo = (const float*)d_in[10];
    const float* bo = (const float*)d_in[11];
    float* out = (float*)d_out;

    const size_t NELEM = (size_t)BB * SS * DD;  // 4M
    float* Qf = (float*)d_ws;
    float* Kf = Qf + NELEM;
    float* Vf = Kf + NELEM;
    float* Cf = Vf + NELEM;

    dim3 grid(DD / 64, (BB * SS) / 64);  // 16 x 64
    gemm_bias<true><<<grid, 256, 0, stream>>>(q, Wq, bq, Qf);
    gemm_bias<true><<<grid, 256, 0, stream>>>(k, Wk, bk, Kf);
    gemm_bias<true><<<grid, 256, 0, stream>>>(v, Wv, bv, Vf);

    attn_mfma<<<BB * HH * (SS / 64), 256, 0, stream>>>(Qf, Kf, Vf, mask, Cf);

    gemm_bias<false><<<grid, 256, 0, stream>>>(Cf, Wo, bo, out);
}

// Round 4
// 512.625 us; speedup vs baseline: 15.7260x; 1.8459x over previous
//
#include <hip/hip_runtime.h>
#include <hip/hip_bf16.h>

#define BB 2
#define SS 2048
#define DD 1024
#define HH 16
#define DKK 64
// M = BB*SS = 4096, N = K = DD = 1024

typedef __hip_bfloat16 bf16;
using frag_ab = __attribute__((ext_vector_type(8))) short;  // 8 bf16 (4 VGPRs)
using frag_cd = __attribute__((ext_vector_type(4))) float;  // 4 fp32

__device__ inline unsigned short f2bf(float f) {
    bf16 h = __float2bfloat16(f);
    return *reinterpret_cast<unsigned short*>(&h);
}

// ---------------- bf16-MFMA GEMM: C = A @ W^T + bias ----------------
// A: [M=4096, K=1024] fp32 row-major; W: [N=1024, K=1024] fp32 row-major.
// 128x128 tile, BK=32, 256 threads (4 waves), wave -> 64x64 subtile (4x4 MFMA).
// SCATTER=true : write fp32 into [B,H,S,DK]; false: fp32 [M,N].
template <bool SCATTER>
__global__ __launch_bounds__(256) void gemm_mfma(const float* __restrict__ A,
                                                 const float* __restrict__ W,
                                                 const float* __restrict__ bias,
                                                 float* __restrict__ out) {
    __shared__ unsigned short As[128][40];  // stride 80 B (16B-aligned frags)
    __shared__ unsigned short Bs[128][40];

    int t = threadIdx.x;
    int m0 = blockIdx.y * 128;
    int n0 = blockIdx.x * 128;
    int w = t >> 6, lane = t & 63;
    int quad = lane >> 4, l16 = lane & 15;
    int wm = w >> 1, wn = w & 1;  // wave -> (row,col) 64-subtile

    frag_cd acc[4][4];
#pragma unroll
    for (int mt = 0; mt < 4; ++mt)
#pragma unroll
        for (int nt = 0; nt < 4; ++nt) acc[mt][nt] = frag_cd{0.f, 0.f, 0.f, 0.f};

    for (int k0 = 0; k0 < DD; k0 += 32) {
        if (k0) __syncthreads();
        // ---- stage: fp32 -> bf16 into LDS (each thread 4 float4 per operand) ----
#pragma unroll
        for (int i = 0; i < 4; ++i) {
            int vid = t + i * 256;            // 0..1023
            int row = vid >> 3;               // 0..127
            int kc = (vid & 7) * 4;           // 0,4,..,28
            float4 a4 = *(const float4*)&A[(size_t)(m0 + row) * DD + k0 + kc];
            ushort4 ua;
            ua.x = f2bf(a4.x); ua.y = f2bf(a4.y); ua.z = f2bf(a4.z); ua.w = f2bf(a4.w);
            *(ushort4*)&As[row][kc] = ua;
            float4 b4 = *(const float4*)&W[(size_t)(n0 + row) * DD + k0 + kc];
            ushort4 ub;
            ub.x = f2bf(b4.x); ub.y = f2bf(b4.y); ub.z = f2bf(b4.z); ub.w = f2bf(b4.w);
            *(ushort4*)&Bs[row][kc] = ub;
        }
        __syncthreads();

        // ---- compute: 8 ds_read_b128 + 16 MFMA per wave ----
        frag_ab af[4], bfr[4];
#pragma unroll
        for (int mt = 0; mt < 4; ++mt)
            af[mt] = *(const frag_ab*)&As[wm * 64 + mt * 16 + l16][quad * 8];
#pragma unroll
        for (int nt = 0; nt < 4; ++nt)
            bfr[nt] = *(const frag_ab*)&Bs[wn * 64 + nt * 16 + l16][quad * 8];
#pragma unroll
        for (int mt = 0; mt < 4; ++mt)
#pragma unroll
            for (int nt = 0; nt < 4; ++nt)
                acc[mt][nt] = __builtin_amdgcn_mfma_f32_16x16x32_bf16(
                    af[mt], bfr[nt], acc[mt][nt], 0, 0, 0);
    }

    // ---- epilogue: C/D layout col=l16, row=quad*4+r ----
#pragma unroll
    for (int nt = 0; nt < 4; ++nt) {
        int n = n0 + wn * 64 + nt * 16 + l16;
        float bv = bias[n];
#pragma unroll
        for (int mt = 0; mt < 4; ++mt) {
#pragma unroll
            for (int r = 0; r < 4; ++r) {
                int m = m0 + wm * 64 + mt * 16 + quad * 4 + r;
                float val = acc[mt][nt][r] + bv;
                if (SCATTER) {
                    int b_ = m / SS, s_ = m % SS;
                    int h_ = n / DKK, d_ = n % DKK;
                    out[(((size_t)b_ * HH + h_) * SS + s_) * DKK + d_] = val;
                } else {
                    out[(size_t)m * DD + n] = val;
                }
            }
        }
    }
}

// ---------------- flash attention with bf16 MFMA (unchanged from R3) ----------------
__global__ __launch_bounds__(256) void attn_mfma(const float* __restrict__ Q,
                                                 const float* __restrict__ K,
                                                 const float* __restrict__ V,
                                                 const int* __restrict__ mask,
                                                 float* __restrict__ C) {
    __shared__ unsigned short Qs[64][72];
    __shared__ unsigned short Ks[64][72];
    __shared__ unsigned short Vt[64][72];
    __shared__ unsigned short Pw[4][16][72];

    int blk = blockIdx.x;
    int qt = blk & 31;
    int bh = blk >> 5;
    int h = bh & 15;
    int b = bh >> 4;
    int q0 = qt * 64;

    const float* Qg = Q + ((size_t)bh * SS + q0) * DKK;
    const float* Kb = K + (size_t)bh * SS * DKK;
    const float* Vb = V + (size_t)bh * SS * DKK;

    int t = threadIdx.x;
    int w = t >> 6;
    int lane = t & 63;
    int quad = lane >> 4;
    int l16 = lane & 15;

    {
        int row = t >> 2;
        int d0 = (t & 3) * 16;
#pragma unroll
        for (int i = 0; i < 4; ++i) {
            float4 v4 = *(const float4*)&Qg[(size_t)row * DKK + d0 + 4 * i];
            ushort4 u;
            u.x = f2bf(v4.x * 0.125f); u.y = f2bf(v4.y * 0.125f);
            u.z = f2bf(v4.z * 0.125f); u.w = f2bf(v4.w * 0.125f);
            *(ushort4*)&Qs[row][d0 + 4 * i] = u;
        }
    }
    __syncthreads();

    int qrow = w * 16 + l16;
    frag_ab aq0 = *(const frag_ab*)&Qs[qrow][quad * 8];
    frag_ab aq1 = *(const frag_ab*)&Qs[qrow][32 + quad * 8];

    frag_cd o[4];
#pragma unroll
    for (int dt = 0; dt < 4; ++dt) o[dt] = frag_cd{0.f, 0.f, 0.f, 0.f};
    float m_prev[4] = {-1e30f, -1e30f, -1e30f, -1e30f};
    float l_run[4] = {0.f, 0.f, 0.f, 0.f};

    for (int kt = 0; kt < 32; ++kt) {
        __syncthreads();
        {
            int row = t >> 2;
            int d0 = (t & 3) * 16;
            const float* Kr = Kb + ((size_t)(kt * 64 + row)) * DKK + d0;
            const float* Vr = Vb + ((size_t)(kt * 64 + row)) * DKK + d0;
#pragma unroll
            for (int i = 0; i < 4; ++i) {
                float4 kv = *(const float4*)&Kr[4 * i];
                ushort4 u;
                u.x = f2bf(kv.x); u.y = f2bf(kv.y); u.z = f2bf(kv.z); u.w = f2bf(kv.w);
                *(ushort4*)&Ks[row][d0 + 4 * i] = u;
                float4 vv = *(const float4*)&Vr[4 * i];
                Vt[d0 + 4 * i + 0][row] = f2bf(vv.x);
                Vt[d0 + 4 * i + 1][row] = f2bf(vv.y);
                Vt[d0 + 4 * i + 2][row] = f2bf(vv.z);
                Vt[d0 + 4 * i + 3][row] = f2bf(vv.w);
            }
        }
        __syncthreads();

        float s[4][4];
#pragma unroll
        for (int nt = 0; nt < 4; ++nt) {
            frag_ab bk0 = *(const frag_ab*)&Ks[nt * 16 + l16][quad * 8];
            frag_ab bk1 = *(const frag_ab*)&Ks[nt * 16 + l16][32 + quad * 8];
            frag_cd sf = frag_cd{0.f, 0.f, 0.f, 0.f};
            sf = __builtin_amdgcn_mfma_f32_16x16x32_bf16(aq0, bk0, sf, 0, 0, 0);
            sf = __builtin_amdgcn_mfma_f32_16x16x32_bf16(aq1, bk1, sf, 0, 0, 0);
#pragma unroll
            for (int r = 0; r < 4; ++r) s[nt][r] = sf[r];
        }

#pragma unroll
        for (int nt = 0; nt < 4; ++nt) {
            int kg = kt * 64 + nt * 16 + l16;
#pragma unroll
            for (int r = 0; r < 4; ++r) {
                int qg = q0 + w * 16 + quad * 4 + r;
                if (mask[(size_t)qg * SS + kg] == 0) s[nt][r] = -1e9f;
            }
        }

        float mnew[4], alpha[4];
#pragma unroll
        for (int r = 0; r < 4; ++r) {
            float mc = fmaxf(fmaxf(s[0][r], s[1][r]), fmaxf(s[2][r], s[3][r]));
#pragma unroll
            for (int d = 1; d < 16; d <<= 1) mc = fmaxf(mc, __shfl_xor(mc, d));
            mnew[r] = fmaxf(m_prev[r], mc);
            alpha[r] = __expf(m_prev[r] - mnew[r]);
        }
        float p[4][4];
#pragma unroll
        for (int r = 0; r < 4; ++r) {
            float ls = 0.f;
#pragma unroll
            for (int nt = 0; nt < 4; ++nt) {
                p[nt][r] = __expf(s[nt][r] - mnew[r]);
                ls += p[nt][r];
            }
#pragma unroll
            for (int d = 1; d < 16; d <<= 1) ls += __shfl_xor(ls, d);
            l_run[r] = l_run[r] * alpha[r] + ls;
            m_prev[r] = mnew[r];
        }
#pragma unroll
        for (int dt = 0; dt < 4; ++dt)
#pragma unroll
            for (int r = 0; r < 4; ++r) o[dt][r] *= alpha[r];

#pragma unroll
        for (int nt = 0; nt < 4; ++nt)
#pragma unroll
            for (int r = 0; r < 4; ++r)
                Pw[w][quad * 4 + r][nt * 16 + l16] = f2bf(p[nt][r]);

        frag_ab ap0 = *(const frag_ab*)&Pw[w][l16][quad * 8];
        frag_ab ap1 = *(const frag_ab*)&Pw[w][l16][32 + quad * 8];

#pragma unroll
        for (int dt = 0; dt < 4; ++dt) {
            frag_ab bv0 = *(const frag_ab*)&Vt[dt * 16 + l16][quad * 8];
            frag_ab bv1 = *(const frag_ab*)&Vt[dt * 16 + l16][32 + quad * 8];
            o[dt] = __builtin_amdgcn_mfma_f32_16x16x32_bf16(ap0, bv0, o[dt], 0, 0, 0);
            o[dt] = __builtin_amdgcn_mfma_f32_16x16x32_bf16(ap1, bv1, o[dt], 0, 0, 0);
        }
    }

    float inv[4];
#pragma unroll
    for (int r = 0; r < 4; ++r) inv[r] = 1.f / l_run[r];
#pragma unroll
    for (int dt = 0; dt < 4; ++dt) {
#pragma unroll
        for (int r = 0; r < 4; ++r) {
            int qg = q0 + w * 16 + quad * 4 + r;
            C[((size_t)b * SS + qg) * DD + h * 64 + dt * 16 + l16] = o[dt][r] * inv[r];
        }
    }
}

extern "C" void kernel_launch(void* const* d_in, const int* in_sizes, int n_in,
                              void* d_out, int out_size, void* d_ws, size_t ws_size,
                              hipStream_t stream) {
    const float* q = (const float*)d_in[0];
    const float* k = (const float*)d_in[1];
    const float* v = (const float*)d_in[2];
    const int* mask = (const int*)d_in[3];
    const float* Wq = (const float*)d_in[4];
    const float* bq = (const float*)d_in[5];
    const float* Wk = (const float*)d_in[6];
    const float* bk = (const float*)d_in[7];
    const float* Wv = (const float*)d_in[8];
    const float* bv = (const float*)d_in[9];
    const float* Wo = (const float*)d_in[10];
    const float* bo = (const float*)d_in[11];
    float* out = (float*)d_out;

    const size_t NELEM = (size_t)BB * SS * DD;  // 4M
    float* Qf = (float*)d_ws;
    float* Kf = Qf + NELEM;
    float* Vf = Kf + NELEM;
    float* Cf = Vf + NELEM;

    dim3 grid(DD / 128, (BB * SS) / 128);  // 8 x 32 = 256 blocks
    gemm_mfma<true><<<grid, 256, 0, stream>>>(q, Wq, bq, Qf);
    gemm_mfma<true><<<grid, 256, 0, stream>>>(k, Wk, bk, Kf);
    gemm_mfma<true><<<grid, 256, 0, stream>>>(v, Wv, bv, Vf);

    attn_mfma<<<BB * HH * (SS / 64), 256, 0, stream>>>(Qf, Kf, Vf, mask, Cf);

    gemm_mfma<false><<<grid, 256, 0, stream>>>(Cf, Wo, bo, out);
}

// Round 5
// 455.497 us; speedup vs baseline: 17.6984x; 1.1254x over previous
//
#include <hip/hip_runtime.h>
#include <hip/hip_bf16.h>

#define BB 2
#define SS 2048
#define DD 1024
#define HH 16
#define DKK 64
// M = BB*SS = 4096, N = K = DD = 1024

typedef __hip_bfloat16 bf16;
using frag_ab = __attribute__((ext_vector_type(8))) short;  // 8 bf16 (4 VGPRs)
using frag_cd = __attribute__((ext_vector_type(4))) float;  // 4 fp32

__device__ inline unsigned short f2bf(float f) {
    bf16 h = __float2bfloat16(f);
    return *reinterpret_cast<unsigned short*>(&h);
}

// column-block swizzle for row-major LDS tiles: breaks the row-stride bank
// aliasing (row stride 72 shorts = 36 dw; rows 16 apart alias mod 32 banks)
__device__ inline int gsw(int row) { return (row ^ (row >> 3)) & 7; }

// ---------------- bf16-MFMA GEMM: C = A @ W^T + bias (unchanged from R4) ----------------
template <bool SCATTER>
__global__ __launch_bounds__(256) void gemm_mfma(const float* __restrict__ A,
                                                 const float* __restrict__ W,
                                                 const float* __restrict__ bias,
                                                 float* __restrict__ out) {
    __shared__ unsigned short As[128][40];
    __shared__ unsigned short Bs[128][40];

    int t = threadIdx.x;
    int m0 = blockIdx.y * 128;
    int n0 = blockIdx.x * 128;
    int w = t >> 6, lane = t & 63;
    int quad = lane >> 4, l16 = lane & 15;
    int wm = w >> 1, wn = w & 1;

    frag_cd acc[4][4];
#pragma unroll
    for (int mt = 0; mt < 4; ++mt)
#pragma unroll
        for (int nt = 0; nt < 4; ++nt) acc[mt][nt] = frag_cd{0.f, 0.f, 0.f, 0.f};

    for (int k0 = 0; k0 < DD; k0 += 32) {
        if (k0) __syncthreads();
#pragma unroll
        for (int i = 0; i < 4; ++i) {
            int vid = t + i * 256;
            int row = vid >> 3;
            int kc = (vid & 7) * 4;
            float4 a4 = *(const float4*)&A[(size_t)(m0 + row) * DD + k0 + kc];
            ushort4 ua;
            ua.x = f2bf(a4.x); ua.y = f2bf(a4.y); ua.z = f2bf(a4.z); ua.w = f2bf(a4.w);
            *(ushort4*)&As[row][kc] = ua;
            float4 b4 = *(const float4*)&W[(size_t)(n0 + row) * DD + k0 + kc];
            ushort4 ub;
            ub.x = f2bf(b4.x); ub.y = f2bf(b4.y); ub.z = f2bf(b4.z); ub.w = f2bf(b4.w);
            *(ushort4*)&Bs[row][kc] = ub;
        }
        __syncthreads();

        frag_ab af[4], bfr[4];
#pragma unroll
        for (int mt = 0; mt < 4; ++mt)
            af[mt] = *(const frag_ab*)&As[wm * 64 + mt * 16 + l16][quad * 8];
#pragma unroll
        for (int nt = 0; nt < 4; ++nt)
            bfr[nt] = *(const frag_ab*)&Bs[wn * 64 + nt * 16 + l16][quad * 8];
#pragma unroll
        for (int mt = 0; mt < 4; ++mt)
#pragma unroll
            for (int nt = 0; nt < 4; ++nt)
                acc[mt][nt] = __builtin_amdgcn_mfma_f32_16x16x32_bf16(
                    af[mt], bfr[nt], acc[mt][nt], 0, 0, 0);
    }

#pragma unroll
    for (int nt = 0; nt < 4; ++nt) {
        int n = n0 + wn * 64 + nt * 16 + l16;
        float bv = bias[n];
#pragma unroll
        for (int mt = 0; mt < 4; ++mt) {
#pragma unroll
            for (int r = 0; r < 4; ++r) {
                int m = m0 + wm * 64 + mt * 16 + quad * 4 + r;
                float val = acc[mt][nt][r] + bv;
                if (SCATTER) {
                    int b_ = m / SS, s_ = m % SS;
                    int h_ = n / DKK, d_ = n % DKK;
                    out[(((size_t)b_ * HH + h_) * SS + s_) * DKK + d_] = val;
                } else {
                    out[(size_t)m * DD + n] = val;
                }
            }
        }
    }
}

// ---------------- flash attention, S^T layout ----------------
// Per block: 64 q rows, sweep 2048 keys in 32 tiles of 64.
// S^T = K_tile · Q^T  => C-layout: col=l16 = q (one q per lane!),
// row = quad*4+reg = key. Softmax state per-lane scalar; reductions are
// in-reg + 2 shuffles. O^T = V^T · P^T accumulated in C-layout (col=q, row=d).
__global__ __launch_bounds__(256) void attn_mfma(const float* __restrict__ Q,
                                                 const float* __restrict__ K,
                                                 const float* __restrict__ V,
                                                 const int* __restrict__ mask,
                                                 float* __restrict__ C) {
    __shared__ unsigned short Qs[64][72];   // [q][d] bf16 (swizzled), pre-scaled
    __shared__ unsigned short Ks[64][72];   // [key][d] bf16 (swizzled)
    __shared__ unsigned short Vt[64][72];   // [d][key] bf16 (swizzled)
    __shared__ unsigned short Pw[4][16][72];// per-wave P^T as [q][key]
    __shared__ int wflag[4];

    int blk = blockIdx.x;
    int qt = blk & 31;
    int bh = blk >> 5;
    int h = bh & 15;
    int b = bh >> 4;
    int q0 = qt * 64;

    const float* Qg = Q + ((size_t)bh * SS + q0) * DKK;
    const float* Kb = K + (size_t)bh * SS * DKK;
    const float* Vb = V + (size_t)bh * SS * DKK;

    int t = threadIdx.x;
    int w = t >> 6;
    int lane = t & 63;
    int quad = lane >> 4;
    int l16 = lane & 15;
    int srow = t >> 2;          // staging row 0..63
    int sd0 = (t & 3) * 16;     // staging col base

    // ---- stage Q tile (scaled by 1/8), swizzled ----
    {
        int g = gsw(srow);
#pragma unroll
        for (int i = 0; i < 4; ++i) {
            int col = sd0 + 4 * i;
            float4 v4 = *(const float4*)&Qg[(size_t)srow * DKK + col];
            ushort4 u;
            u.x = f2bf(v4.x * 0.125f); u.y = f2bf(v4.y * 0.125f);
            u.z = f2bf(v4.z * 0.125f); u.w = f2bf(v4.w * 0.125f);
            int cs = (((col >> 3) ^ g) << 3) + (col & 7);
            *(ushort4*)&Qs[srow][cs] = u;
        }
    }
    __syncthreads();

    // loop-invariant Q B-frags: B[k=d][n=q], n = l16 -> row w*16+l16
    int qr = w * 16 + l16;
    int gq = gsw(qr);
    frag_ab bq0 = *(const frag_ab*)&Qs[qr][(quad ^ gq) << 3];
    frag_ab bq1 = *(const frag_ab*)&Qs[qr][((quad + 4) ^ gq) << 3];

    frag_cd o[4];
#pragma unroll
    for (int dt = 0; dt < 4; ++dt) o[dt] = frag_cd{0.f, 0.f, 0.f, 0.f};
    float m_prev = -1e30f;
    float l_run = 0.f;

    for (int kt = 0; kt < 32; ++kt) {
        __syncthreads();  // (A) prior tile's frag reads complete
        // ---- stage K (row-major swizzled), V (transposed swizzled), mask check ----
        int anyz = 0;
        {
            int g = gsw(srow);
            const float* Kr = Kb + ((size_t)(kt * 64 + srow)) * DKK;
            const float* Vr = Vb + ((size_t)(kt * 64 + srow)) * DKK;
            const int* Mr = mask + (size_t)(q0 + srow) * SS + kt * 64;
#pragma unroll
            for (int i = 0; i < 4; ++i) {
                int col = sd0 + 4 * i;
                float4 kv = *(const float4*)&Kr[col];
                ushort4 uk;
                uk.x = f2bf(kv.x); uk.y = f2bf(kv.y); uk.z = f2bf(kv.z); uk.w = f2bf(kv.w);
                int cs = (((col >> 3) ^ g) << 3) + (col & 7);
                *(ushort4*)&Ks[srow][cs] = uk;

                float4 vv = *(const float4*)&Vr[col];
                unsigned short us[4];
                us[0] = f2bf(vv.x); us[1] = f2bf(vv.y); us[2] = f2bf(vv.z); us[3] = f2bf(vv.w);
#pragma unroll
                for (int j = 0; j < 4; ++j) {
                    int d = col + j;
                    int gv = (d ^ (d >> 3)) & 7;
                    Vt[d][(((srow >> 3) ^ gv) << 3) + (srow & 7)] = us[j];
                }

                int4 m4 = *(const int4*)&Mr[col];
                anyz |= (m4.x == 0) | (m4.y == 0) | (m4.z == 0) | (m4.w == 0);
            }
        }
        if (lane == 0) wflag[w] = (__ballot(anyz) != 0ULL) ? 1 : 0;
        __syncthreads();  // (B)
        bool anyzero = (wflag[0] | wflag[1] | wflag[2] | wflag[3]) != 0;

        // ---- S^T: 4 key-subtiles, A = K rows, B = Q^T ----
        float s[4][4];
#pragma unroll
        for (int nt = 0; nt < 4; ++nt) {
            int kr = nt * 16 + l16;
            int gk = gsw(kr);
            frag_ab ak0 = *(const frag_ab*)&Ks[kr][(quad ^ gk) << 3];
            frag_ab ak1 = *(const frag_ab*)&Ks[kr][((quad + 4) ^ gk) << 3];
            frag_cd sf = frag_cd{0.f, 0.f, 0.f, 0.f};
            sf = __builtin_amdgcn_mfma_f32_16x16x32_bf16(ak0, bq0, sf, 0, 0, 0);
            sf = __builtin_amdgcn_mfma_f32_16x16x32_bf16(ak1, bq1, sf, 0, 0, 0);
#pragma unroll
            for (int r = 0; r < 4; ++r) s[nt][r] = sf[r];
        }

        // ---- mask slow path (block-uniform branch; never taken for all-ones mask) ----
        if (anyzero) {
            int qg = q0 + w * 16 + l16;
#pragma unroll
            for (int nt = 0; nt < 4; ++nt)
#pragma unroll
                for (int r = 0; r < 4; ++r) {
                    int kg = kt * 64 + nt * 16 + quad * 4 + r;
                    if (mask[(size_t)qg * SS + kg] == 0) s[nt][r] = -1e9f;
                }
        }

        // ---- online softmax: per-lane scalar state, 4 shuffles total ----
        float mc = s[0][0];
#pragma unroll
        for (int nt = 0; nt < 4; ++nt)
#pragma unroll
            for (int r = 0; r < 4; ++r) mc = fmaxf(mc, s[nt][r]);
        mc = fmaxf(mc, __shfl_xor(mc, 16));
        mc = fmaxf(mc, __shfl_xor(mc, 32));
        float mnew = fmaxf(m_prev, mc);
        float alpha = __expf(m_prev - mnew);

        float p[4][4];
        float ls = 0.f;
#pragma unroll
        for (int nt = 0; nt < 4; ++nt)
#pragma unroll
            for (int r = 0; r < 4; ++r) {
                p[nt][r] = __expf(s[nt][r] - mnew);
                ls += p[nt][r];
            }
        ls += __shfl_xor(ls, 16);
        ls += __shfl_xor(ls, 32);
        l_run = l_run * alpha + ls;
        m_prev = mnew;

#pragma unroll
        for (int dt = 0; dt < 4; ++dt)
#pragma unroll
            for (int r = 0; r < 4; ++r) o[dt][r] *= alpha;

        // ---- P^T store: Pw[q=l16][key], vectorized ushort4 (keys consecutive) ----
#pragma unroll
        for (int nt = 0; nt < 4; ++nt) {
            ushort4 up;
            up.x = f2bf(p[nt][0]); up.y = f2bf(p[nt][1]);
            up.z = f2bf(p[nt][2]); up.w = f2bf(p[nt][3]);
            *(ushort4*)&Pw[w][l16][nt * 16 + quad * 4] = up;
        }
        frag_ab bp0 = *(const frag_ab*)&Pw[w][l16][quad * 8];
        frag_ab bp1 = *(const frag_ab*)&Pw[w][l16][32 + quad * 8];

        // ---- O^T += V^T · P^T ----
#pragma unroll
        for (int dt = 0; dt < 4; ++dt) {
            int dr = dt * 16 + l16;
            int gv = (dr ^ (dr >> 3)) & 7;
            frag_ab av0 = *(const frag_ab*)&Vt[dr][(quad ^ gv) << 3];
            frag_ab av1 = *(const frag_ab*)&Vt[dr][((quad + 4) ^ gv) << 3];
            o[dt] = __builtin_amdgcn_mfma_f32_16x16x32_bf16(av0, bp0, o[dt], 0, 0, 0);
            o[dt] = __builtin_amdgcn_mfma_f32_16x16x32_bf16(av1, bp1, o[dt], 0, 0, 0);
        }
    }

    // ---- epilogue: O^T C-layout col=l16=q, row=quad*4+r=d -> float4 stores ----
    float inv = 1.f / l_run;
    int qg = q0 + w * 16 + l16;
    float* Crow = C + ((size_t)b * SS + qg) * DD + h * 64;
#pragma unroll
    for (int dt = 0; dt < 4; ++dt) {
        float4 val;
        val.x = o[dt][0] * inv; val.y = o[dt][1] * inv;
        val.z = o[dt][2] * inv; val.w = o[dt][3] * inv;
        *(float4*)&Crow[dt * 16 + quad * 4] = val;
    }
}

extern "C" void kernel_launch(void* const* d_in, const int* in_sizes, int n_in,
                              void* d_out, int out_size, void* d_ws, size_t ws_size,
                              hipStream_t stream) {
    const float* q = (const float*)d_in[0];
    const float* k = (const float*)d_in[1];
    const float* v = (const float*)d_in[2];
    const int* mask = (const int*)d_in[3];
    const float* Wq = (const float*)d_in[4];
    const float* bq = (const float*)d_in[5];
    const float* Wk = (const float*)d_in[6];
    const float* bk = (const float*)d_in[7];
    const float* Wv = (const float*)d_in[8];
    const float* bv = (const float*)d_in[9];
    const float* Wo = (const float*)d_in[10];
    const float* bo = (const float*)d_in[11];
    float* out = (float*)d_out;

    const size_t NELEM = (size_t)BB * SS * DD;  // 4M
    float* Qf = (float*)d_ws;
    float* Kf = Qf + NELEM;
    float* Vf = Kf + NELEM;
    float* Cf = Vf + NELEM;

    dim3 grid(DD / 128, (BB * SS) / 128);  // 8 x 32 = 256 blocks
    gemm_mfma<true><<<grid, 256, 0, stream>>>(q, Wq, bq, Qf);
    gemm_mfma<true><<<grid, 256, 0, stream>>>(k, Wk, bk, Kf);
    gemm_mfma<true><<<grid, 256, 0, stream>>>(v, Wv, bv, Vf);

    attn_mfma<<<BB * HH * (SS / 64), 256, 0, stream>>>(Qf, Kf, Vf, mask, Cf);

    gemm_mfma<false><<<grid, 256, 0, stream>>>(Cf, Wo, bo, out);
}

// Round 6
// 391.748 us; speedup vs baseline: 20.5785x; 1.1627x over previous
//
#include <hip/hip_runtime.h>
#include <hip/hip_bf16.h>

#define BB 2
#define SS 2048
#define DD 1024
#define HH 16
#define DKK 64
// M = BB*SS = 4096, N = K = DD = 1024

typedef __hip_bfloat16 bf16;
typedef unsigned short u16;
using frag_ab = __attribute__((ext_vector_type(8))) short;  // 8 bf16 (4 VGPRs)
using frag_cd = __attribute__((ext_vector_type(4))) float;  // 4 fp32

__device__ inline u16 f2bf(float f) {
    bf16 h = __float2bfloat16(f);
    return *reinterpret_cast<u16*>(&h);
}

// ---------------- bf16-MFMA GEMM: C = A @ W^T + bias ----------------
// MODE 0: fp32 out [M,N]
// MODE 1: bf16 out [B,H,S,DK], value scaled by `scale` (Q:0.125, K:1)
// MODE 2: bf16 out [B,H,DK,S]  (V transposed)
template <int MODE>
__global__ __launch_bounds__(256) void gemm_mfma(const float* __restrict__ A,
                                                 const float* __restrict__ W,
                                                 const float* __restrict__ bias,
                                                 float* __restrict__ outF,
                                                 u16* __restrict__ outB,
                                                 float scale) {
    __shared__ u16 As[128][40];
    __shared__ u16 Bs[128][40];

    int t = threadIdx.x;
    int m0 = blockIdx.y * 128;
    int n0 = blockIdx.x * 128;
    int w = t >> 6, lane = t & 63;
    int quad = lane >> 4, l16 = lane & 15;
    int wm = w >> 1, wn = w & 1;

    frag_cd acc[4][4];
#pragma unroll
    for (int mt = 0; mt < 4; ++mt)
#pragma unroll
        for (int nt = 0; nt < 4; ++nt) acc[mt][nt] = frag_cd{0.f, 0.f, 0.f, 0.f};

    for (int k0 = 0; k0 < DD; k0 += 32) {
        if (k0) __syncthreads();
#pragma unroll
        for (int i = 0; i < 4; ++i) {
            int vid = t + i * 256;
            int row = vid >> 3;
            int kc = (vid & 7) * 4;
            float4 a4 = *(const float4*)&A[(size_t)(m0 + row) * DD + k0 + kc];
            ushort4 ua;
            ua.x = f2bf(a4.x); ua.y = f2bf(a4.y); ua.z = f2bf(a4.z); ua.w = f2bf(a4.w);
            *(ushort4*)&As[row][kc] = ua;
            float4 b4 = *(const float4*)&W[(size_t)(n0 + row) * DD + k0 + kc];
            ushort4 ub;
            ub.x = f2bf(b4.x); ub.y = f2bf(b4.y); ub.z = f2bf(b4.z); ub.w = f2bf(b4.w);
            *(ushort4*)&Bs[row][kc] = ub;
        }
        __syncthreads();

        frag_ab af[4], bfr[4];
#pragma unroll
        for (int mt = 0; mt < 4; ++mt)
            af[mt] = *(const frag_ab*)&As[wm * 64 + mt * 16 + l16][quad * 8];
#pragma unroll
        for (int nt = 0; nt < 4; ++nt)
            bfr[nt] = *(const frag_ab*)&Bs[wn * 64 + nt * 16 + l16][quad * 8];
#pragma unroll
        for (int mt = 0; mt < 4; ++mt)
#pragma unroll
            for (int nt = 0; nt < 4; ++nt)
                acc[mt][nt] = __builtin_amdgcn_mfma_f32_16x16x32_bf16(
                    af[mt], bfr[nt], acc[mt][nt], 0, 0, 0);
    }

#pragma unroll
    for (int nt = 0; nt < 4; ++nt) {
        int n = n0 + wn * 64 + nt * 16 + l16;
        float bv = bias[n];
        int h_ = n >> 6, d_ = n & 63;
#pragma unroll
        for (int mt = 0; mt < 4; ++mt) {
            int mb = m0 + wm * 64 + mt * 16 + quad * 4;
            if (MODE == 2) {
                int b_ = mb >> 11, s_ = mb & 2047;
                ushort4 u;
                u.x = f2bf(acc[mt][nt][0] + bv);
                u.y = f2bf(acc[mt][nt][1] + bv);
                u.z = f2bf(acc[mt][nt][2] + bv);
                u.w = f2bf(acc[mt][nt][3] + bv);
                *(ushort4*)&outB[((size_t)(b_ * HH + h_) * DKK + d_) * SS + s_] = u;
            } else {
#pragma unroll
                for (int r = 0; r < 4; ++r) {
                    int m = mb + r;
                    float val = acc[mt][nt][r] + bv;
                    if (MODE == 0) {
                        outF[(size_t)m * DD + n] = val;
                    } else {  // MODE 1
                        int b_ = m >> 11, s_ = m & 2047;
                        outB[((size_t)(b_ * HH + h_) * SS + s_) * DKK + d_] =
                            f2bf(val * scale);
                    }
                }
            }
        }
    }
}

// ---------------- mask tile flags: flags[qt*32+kt] = any-zero in 64x64 tile ----
__global__ __launch_bounds__(256) void mask_tiles(const int* __restrict__ mask,
                                                  int* __restrict__ flags) {
    int tile = blockIdx.x;
    int qt = tile >> 5, kt = tile & 31;
    __shared__ int f;
    if (threadIdx.x == 0) f = 0;
    __syncthreads();
    int q = qt * 64 + (threadIdx.x >> 2);
    const int4* row = (const int4*)(mask + (size_t)q * SS + kt * 64 + (threadIdx.x & 3) * 16);
    int anyz = 0;
#pragma unroll
    for (int i = 0; i < 4; ++i) {
        int4 m4 = row[i];
        anyz |= (m4.x == 0) | (m4.y == 0) | (m4.z == 0) | (m4.w == 0);
    }
    if (anyz) f = 1;
    __syncthreads();
    if (threadIdx.x == 0) flags[tile] = f;
}

// ---------------- flash attention, S^T layout, bf16 inputs ----------------
// Qb: [B,H,S,DK] bf16 pre-scaled; Kb: [B,H,S,DK] bf16; Vb: [B,H,DK,S] bf16.
// S^T = K_tile · Q^T: C-layout col=l16=q, row=quad*4+reg=key -> per-lane softmax.
// O^T = V^T · P^T accumulated in C-layout (col=q, row=d). Writes fp32 [B,S,D].
__global__ __launch_bounds__(256) void attn_mfma(const u16* __restrict__ Qb,
                                                 const u16* __restrict__ Kb,
                                                 const u16* __restrict__ Vb,
                                                 const int* __restrict__ mask,
                                                 const int* __restrict__ flags,
                                                 float* __restrict__ C) {
    __shared__ u16 Qs[64 * 64];
    __shared__ u16 Ks[64 * 64];
    __shared__ u16 Vt[64 * 64];      // [d][key]
    __shared__ u16 Pw[4][16 * 72];   // per-wave P^T [q][key], padded stride

    int blk = blockIdx.x;
    int qt = blk & 31;
    int bh = blk >> 5;
    int h = bh & 15;
    int b = bh >> 4;
    int q0 = qt * 64;

    const u16* Qg = Qb + ((size_t)bh * SS + q0) * DKK;  // 4096 shorts linear
    const u16* Kg = Kb + (size_t)bh * SS * DKK;
    const u16* Vg = Vb + (size_t)bh * DKK * SS;

    int t = threadIdx.x;
    int w = t >> 6;
    int lane = t & 63;
    int quad = lane >> 4;
    int l16 = lane & 15;

    // ---- stage Q tile (already bf16 + scaled): plain 16B copies ----
    ((int4*)Qs)[2 * t] = ((const int4*)Qg)[2 * t];
    ((int4*)Qs)[2 * t + 1] = ((const int4*)Qg)[2 * t + 1];
    __syncthreads();

    int qr = w * 16 + l16;
    frag_ab bq0 = *(const frag_ab*)&Qs[qr * 64 + quad * 8];
    frag_ab bq1 = *(const frag_ab*)&Qs[qr * 64 + 32 + quad * 8];

    frag_cd o[4];
#pragma unroll
    for (int dt = 0; dt < 4; ++dt) o[dt] = frag_cd{0.f, 0.f, 0.f, 0.f};
    float m_prev = -1e30f;
    float l_run = 0.f;

    // V staging geometry: thread covers d-row (t>>2), key chunk (t&3)*16
    int vd = t >> 2;
    int vc = (t & 3) * 16;

    // ---- register prefetch of tile 0 ----
    int4 kr0, kr1, vr0, vr1;
    {
        const int4* Kt = (const int4*)(Kg);
        kr0 = Kt[2 * t]; kr1 = Kt[2 * t + 1];
        const int4* Vr = (const int4*)(Vg + (size_t)vd * SS + vc);
        vr0 = Vr[0]; vr1 = Vr[1];
    }

    for (int kt = 0; kt < 32; ++kt) {
        if (kt) __syncthreads();  // (A) prior tile's frag reads complete
        // ---- write prefetched regs to LDS ----
        ((int4*)Ks)[2 * t] = kr0;
        ((int4*)Ks)[2 * t + 1] = kr1;
        *(int4*)&Vt[vd * 64 + vc] = vr0;
        *(int4*)&Vt[vd * 64 + vc + 8] = vr1;
        // ---- prefetch next tile (overlaps compute below) ----
        if (kt < 31) {
            const int4* Kt = (const int4*)(Kg + (size_t)(kt + 1) * 4096);
            kr0 = Kt[2 * t]; kr1 = Kt[2 * t + 1];
            const int4* Vr = (const int4*)(Vg + (size_t)vd * SS + (kt + 1) * 64 + vc);
            vr0 = Vr[0]; vr1 = Vr[1];
        }
        int anyzero = flags[(qt << 5) + kt];
        __syncthreads();  // (B) staged tile visible

        // ---- S^T: 4 key-subtiles, A = K rows, B = Q^T ----
        float s[4][4];
#pragma unroll
        for (int nt = 0; nt < 4; ++nt) {
            int kr = nt * 16 + l16;
            frag_ab ak0 = *(const frag_ab*)&Ks[kr * 64 + quad * 8];
            frag_ab ak1 = *(const frag_ab*)&Ks[kr * 64 + 32 + quad * 8];
            frag_cd sf = frag_cd{0.f, 0.f, 0.f, 0.f};
            sf = __builtin_amdgcn_mfma_f32_16x16x32_bf16(ak0, bq0, sf, 0, 0, 0);
            sf = __builtin_amdgcn_mfma_f32_16x16x32_bf16(ak1, bq1, sf, 0, 0, 0);
#pragma unroll
            for (int r = 0; r < 4; ++r) s[nt][r] = sf[r];
        }

        // ---- mask slow path (block-uniform; not taken for all-ones mask) ----
        if (anyzero) {
            int qg = q0 + w * 16 + l16;
#pragma unroll
            for (int nt = 0; nt < 4; ++nt)
#pragma unroll
                for (int r = 0; r < 4; ++r) {
                    int kg = kt * 64 + nt * 16 + quad * 4 + r;
                    if (mask[(size_t)qg * SS + kg] == 0) s[nt][r] = -1e9f;
                }
        }

        // ---- online softmax: per-lane scalar state ----
        float mc = s[0][0];
#pragma unroll
        for (int nt = 0; nt < 4; ++nt)
#pragma unroll
            for (int r = 0; r < 4; ++r) mc = fmaxf(mc, s[nt][r]);
        mc = fmaxf(mc, __shfl_xor(mc, 16));
        mc = fmaxf(mc, __shfl_xor(mc, 32));
        float mnew = fmaxf(m_prev, mc);
        float alpha = __expf(m_prev - mnew);

        float p[4][4];
        float ls = 0.f;
#pragma unroll
        for (int nt = 0; nt < 4; ++nt)
#pragma unroll
            for (int r = 0; r < 4; ++r) {
                p[nt][r] = __expf(s[nt][r] - mnew);
                ls += p[nt][r];
            }
        ls += __shfl_xor(ls, 16);
        ls += __shfl_xor(ls, 32);
        l_run = l_run * alpha + ls;
        m_prev = mnew;

#pragma unroll
        for (int dt = 0; dt < 4; ++dt)
#pragma unroll
            for (int r = 0; r < 4; ++r) o[dt][r] *= alpha;

        // ---- P^T store: Pw[q=l16][key], ushort4 (keys consecutive) ----
#pragma unroll
        for (int nt = 0; nt < 4; ++nt) {
            ushort4 up;
            up.x = f2bf(p[nt][0]); up.y = f2bf(p[nt][1]);
            up.z = f2bf(p[nt][2]); up.w = f2bf(p[nt][3]);
            *(ushort4*)&Pw[w][l16 * 72 + nt * 16 + quad * 4] = up;
        }
        frag_ab bp0 = *(const frag_ab*)&Pw[w][l16 * 72 + quad * 8];
        frag_ab bp1 = *(const frag_ab*)&Pw[w][l16 * 72 + 32 + quad * 8];

        // ---- O^T += V^T · P^T ----
#pragma unroll
        for (int dt = 0; dt < 4; ++dt) {
            int dr = dt * 16 + l16;
            frag_ab av0 = *(const frag_ab*)&Vt[dr * 64 + quad * 8];
            frag_ab av1 = *(const frag_ab*)&Vt[dr * 64 + 32 + quad * 8];
            o[dt] = __builtin_amdgcn_mfma_f32_16x16x32_bf16(av0, bp0, o[dt], 0, 0, 0);
            o[dt] = __builtin_amdgcn_mfma_f32_16x16x32_bf16(av1, bp1, o[dt], 0, 0, 0);
        }
    }

    // ---- epilogue: O^T C-layout col=l16=q, row=quad*4+r=d -> float4 stores ----
    float inv = 1.f / l_run;
    int qg = q0 + w * 16 + l16;
    float* Crow = C + ((size_t)b * SS + qg) * DD + h * 64;
#pragma unroll
    for (int dt = 0; dt < 4; ++dt) {
        float4 val;
        val.x = o[dt][0] * inv; val.y = o[dt][1] * inv;
        val.z = o[dt][2] * inv; val.w = o[dt][3] * inv;
        *(float4*)&Crow[dt * 16 + quad * 4] = val;
    }
}

extern "C" void kernel_launch(void* const* d_in, const int* in_sizes, int n_in,
                              void* d_out, int out_size, void* d_ws, size_t ws_size,
                              hipStream_t stream) {
    const float* q = (const float*)d_in[0];
    const float* k = (const float*)d_in[1];
    const float* v = (const float*)d_in[2];
    const int* mask = (const int*)d_in[3];
    const float* Wq = (const float*)d_in[4];
    const float* bq = (const float*)d_in[5];
    const float* Wk = (const float*)d_in[6];
    const float* bk = (const float*)d_in[7];
    const float* Wv = (const float*)d_in[8];
    const float* bv = (const float*)d_in[9];
    const float* Wo = (const float*)d_in[10];
    const float* bo = (const float*)d_in[11];
    float* out = (float*)d_out;

    const size_t NELEM = (size_t)BB * SS * DD;  // 4M
    char* ws = (char*)d_ws;
    u16* Qb = (u16*)ws;                          // 8 MB
    u16* Kb = (u16*)(ws + 8u * 1024 * 1024);     // 8 MB
    u16* Vb = (u16*)(ws + 16u * 1024 * 1024);    // 8 MB
    float* Cf = (float*)(ws + 24u * 1024 * 1024);// 16 MB
    int* flags = (int*)(ws + 40u * 1024 * 1024); // 4 KB

    mask_tiles<<<1024, 256, 0, stream>>>(mask, flags);

    dim3 grid(DD / 128, (BB * SS) / 128);  // 8 x 32 = 256 blocks
    gemm_mfma<1><<<grid, 256, 0, stream>>>(q, Wq, bq, nullptr, Qb, 0.125f);
    gemm_mfma<1><<<grid, 256, 0, stream>>>(k, Wk, bk, nullptr, Kb, 1.0f);
    gemm_mfma<2><<<grid, 256, 0, stream>>>(v, Wv, bv, nullptr, Vb, 1.0f);

    attn_mfma<<<BB * HH * (SS / 64), 256, 0, stream>>>(Qb, Kb, Vb, mask, flags, Cf);

    gemm_mfma<0><<<grid, 256, 0, stream>>>(Cf, Wo, bo, out, nullptr, 1.0f);
}

// Round 7
// 298.796 us; speedup vs baseline: 26.9802x; 1.3111x over previous
//
#include <hip/hip_runtime.h>
#include <hip/hip_bf16.h>

#define BB 2
#define SS 2048
#define DD 1024
#define HH 16
#define DKK 64
// M = BB*SS = 4096, N = K = DD = 1024

typedef __hip_bfloat16 bf16;
typedef unsigned short u16;
using frag_ab = __attribute__((ext_vector_type(8))) short;  // 8 bf16 (4 VGPRs)
using frag_cd = __attribute__((ext_vector_type(4))) float;  // 4 fp32

__device__ inline u16 f2bf(float f) {
    bf16 h = __float2bfloat16(f);
    return *reinterpret_cast<u16*>(&h);
}

// async global->LDS, 16B per lane. LDS side is wave-uniform base + lane*16,
// so per-lane lds ptrs must be linear in lane order (they are, below).
__device__ inline void gld16(const void* g, void* l) {
    __builtin_amdgcn_global_load_lds((const __attribute__((address_space(1))) void*)g,
                                     (__attribute__((address_space(3))) void*)l,
                                     16, 0, 0);
}

// ---------------- prep: fp32->bf16 converts + mask tile flags ----------------
// blocks 0..6143: q/k/v (2048 each); 6144..8191: Wq/Wk/Wv/Wo (512 each);
// 8192..9215: mask 64x64 tile any-zero flags.
__global__ __launch_bounds__(256) void prep(
    const float* __restrict__ q, const float* __restrict__ k, const float* __restrict__ v,
    const float* __restrict__ Wq, const float* __restrict__ Wk,
    const float* __restrict__ Wv, const float* __restrict__ Wo,
    u16* __restrict__ qb, u16* __restrict__ kb, u16* __restrict__ vb,
    u16* __restrict__ Wqb, u16* __restrict__ Wkb, u16* __restrict__ Wvb, u16* __restrict__ Wob,
    const int* __restrict__ mask, int* __restrict__ flags) {
    int bid = blockIdx.x;
    int t = threadIdx.x;
    if (bid < 8192) {
        const float* src;
        u16* dst;
        int local;
        if (bid < 6144) {
            int ts = bid >> 11;
            local = bid & 2047;
            src = ts == 0 ? q : (ts == 1 ? k : v);
            dst = ts == 0 ? qb : (ts == 1 ? kb : vb);
        } else {
            int wsel = (bid - 6144) >> 9;
            local = (bid - 6144) & 511;
            src = wsel == 0 ? Wq : (wsel == 1 ? Wk : (wsel == 2 ? Wv : Wo));
            dst = wsel == 0 ? Wqb : (wsel == 1 ? Wkb : (wsel == 2 ? Wvb : Wob));
        }
        size_t base = (size_t)local * 2048 + t * 8;
        float4 a = *(const float4*)&src[base];
        float4 b = *(const float4*)&src[base + 4];
        ushort4 u0, u1;
        u0.x = f2bf(a.x); u0.y = f2bf(a.y); u0.z = f2bf(a.z); u0.w = f2bf(a.w);
        u1.x = f2bf(b.x); u1.y = f2bf(b.y); u1.z = f2bf(b.z); u1.w = f2bf(b.w);
        *(ushort4*)&dst[base] = u0;
        *(ushort4*)&dst[base + 4] = u1;
    } else {
        int tile = bid - 8192;
        int qt = tile >> 5, kt = tile & 31;
        __shared__ int f;
        if (t == 0) f = 0;
        __syncthreads();
        int qq = qt * 64 + (t >> 2);
        const int4* row = (const int4*)(mask + (size_t)qq * SS + kt * 64 + (t & 3) * 16);
        int anyz = 0;
#pragma unroll
        for (int i = 0; i < 4; ++i) {
            int4 m4 = row[i];
            anyz |= (m4.x == 0) | (m4.y == 0) | (m4.z == 0) | (m4.w == 0);
        }
        if (anyz) f = 1;
        __syncthreads();
        if (t == 0) flags[tile] = f;
    }
}

// ---------------- fused QKV GEMM (bf16 in, bf16 out), m97-style staging ----------------
// z=0: Q -> [B,H,S,DK] scaled 0.125; z=1: K -> [B,H,S,DK]; z=2: V -> [B,H,DK,S].
// 128x128 tile, BK=32, global_load_lds width-16 staging, 2-barrier K-loop.
__global__ __launch_bounds__(256) void qkv_gemm(
    const u16* __restrict__ Aq, const u16* __restrict__ Ak, const u16* __restrict__ Av,
    const u16* __restrict__ Wq, const u16* __restrict__ Wk, const u16* __restrict__ Wv,
    const float* __restrict__ bq, const float* __restrict__ bk, const float* __restrict__ bv,
    u16* __restrict__ Qo, u16* __restrict__ Ko, u16* __restrict__ Vo) {
    __shared__ u16 As[128 * 32];
    __shared__ u16 Bs[128 * 32];

    int z = blockIdx.z;
    const u16* A = z == 0 ? Aq : (z == 1 ? Ak : Av);
    const u16* W = z == 0 ? Wq : (z == 1 ? Wk : Wv);
    const float* bias = z == 0 ? bq : (z == 1 ? bk : bv);
    u16* out = z == 0 ? Qo : (z == 1 ? Ko : Vo);

    int t = threadIdx.x;
    int m0 = blockIdx.y * 128;
    int n0 = blockIdx.x * 128;
    int w = t >> 6, lane = t & 63;
    int quad = lane >> 4, l16 = lane & 15;
    int wm = w >> 1, wn = w & 1;

    const u16* Ab = A + (size_t)m0 * DD;
    const u16* Wb = W + (size_t)n0 * DD;

    frag_cd acc[4][4];
#pragma unroll
    for (int mt = 0; mt < 4; ++mt)
#pragma unroll
        for (int nt = 0; nt < 4; ++nt) acc[mt][nt] = frag_cd{0.f, 0.f, 0.f, 0.f};

    for (int k0 = 0; k0 < DD; k0 += 32) {
        if (k0) __syncthreads();
#pragma unroll
        for (int i = 0; i < 2; ++i) {
            int c = t + i * 256;          // 0..511 chunk of 8 bf16
            int row = c >> 2, kc = (c & 3) * 8;
            gld16(Ab + (size_t)row * DD + k0 + kc, &As[c * 8]);
            gld16(Wb + (size_t)row * DD + k0 + kc, &Bs[c * 8]);
        }
        __syncthreads();

        frag_ab af[4], bfr[4];
#pragma unroll
        for (int mt = 0; mt < 4; ++mt)
            af[mt] = *(const frag_ab*)&As[(wm * 64 + mt * 16 + l16) * 32 + quad * 8];
#pragma unroll
        for (int nt = 0; nt < 4; ++nt)
            bfr[nt] = *(const frag_ab*)&Bs[(wn * 64 + nt * 16 + l16) * 32 + quad * 8];
#pragma unroll
        for (int mt = 0; mt < 4; ++mt)
#pragma unroll
            for (int nt = 0; nt < 4; ++nt)
                acc[mt][nt] = __builtin_amdgcn_mfma_f32_16x16x32_bf16(
                    af[mt], bfr[nt], acc[mt][nt], 0, 0, 0);
    }

    float scale = z == 0 ? 0.125f : 1.0f;
#pragma unroll
    for (int nt = 0; nt < 4; ++nt) {
        int n = n0 + wn * 64 + nt * 16 + l16;
        float bv_ = bias[n];
        int h_ = n >> 6, d_ = n & 63;
#pragma unroll
        for (int mt = 0; mt < 4; ++mt) {
            int mb = m0 + wm * 64 + mt * 16 + quad * 4;
            int b_ = mb >> 11, s_ = mb & 2047;
            if (z == 2) {
                ushort4 u;
                u.x = f2bf(acc[mt][nt][0] + bv_);
                u.y = f2bf(acc[mt][nt][1] + bv_);
                u.z = f2bf(acc[mt][nt][2] + bv_);
                u.w = f2bf(acc[mt][nt][3] + bv_);
                *(ushort4*)&out[((size_t)(b_ * HH + h_) * DKK + d_) * SS + s_] = u;
            } else {
#pragma unroll
                for (int r = 0; r < 4; ++r)
                    out[((size_t)(b_ * HH + h_) * SS + s_ + r) * DKK + d_] =
                        f2bf((acc[mt][nt][r] + bv_) * scale);
            }
        }
    }
}

// ---------------- output GEMM: fp32 out = Cw(bf16) @ Wo^T + bo ----------------
__global__ __launch_bounds__(256) void out_gemm(const u16* __restrict__ A,
                                                const u16* __restrict__ W,
                                                const float* __restrict__ bias,
                                                float* __restrict__ out) {
    __shared__ u16 As[128 * 32];
    __shared__ u16 Bs[128 * 32];

    int t = threadIdx.x;
    int m0 = blockIdx.y * 128;
    int n0 = blockIdx.x * 128;
    int w = t >> 6, lane = t & 63;
    int quad = lane >> 4, l16 = lane & 15;
    int wm = w >> 1, wn = w & 1;

    const u16* Ab = A + (size_t)m0 * DD;
    const u16* Wb = W + (size_t)n0 * DD;

    frag_cd acc[4][4];
#pragma unroll
    for (int mt = 0; mt < 4; ++mt)
#pragma unroll
        for (int nt = 0; nt < 4; ++nt) acc[mt][nt] = frag_cd{0.f, 0.f, 0.f, 0.f};

    for (int k0 = 0; k0 < DD; k0 += 32) {
        if (k0) __syncthreads();
#pragma unroll
        for (int i = 0; i < 2; ++i) {
            int c = t + i * 256;
            int row = c >> 2, kc = (c & 3) * 8;
            gld16(Ab + (size_t)row * DD + k0 + kc, &As[c * 8]);
            gld16(Wb + (size_t)row * DD + k0 + kc, &Bs[c * 8]);
        }
        __syncthreads();

        frag_ab af[4], bfr[4];
#pragma unroll
        for (int mt = 0; mt < 4; ++mt)
            af[mt] = *(const frag_ab*)&As[(wm * 64 + mt * 16 + l16) * 32 + quad * 8];
#pragma unroll
        for (int nt = 0; nt < 4; ++nt)
            bfr[nt] = *(const frag_ab*)&Bs[(wn * 64 + nt * 16 + l16) * 32 + quad * 8];
#pragma unroll
        for (int mt = 0; mt < 4; ++mt)
#pragma unroll
            for (int nt = 0; nt < 4; ++nt)
                acc[mt][nt] = __builtin_amdgcn_mfma_f32_16x16x32_bf16(
                    af[mt], bfr[nt], acc[mt][nt], 0, 0, 0);
    }

#pragma unroll
    for (int nt = 0; nt < 4; ++nt) {
        int n = n0 + wn * 64 + nt * 16 + l16;
        float bv_ = bias[n];
#pragma unroll
        for (int mt = 0; mt < 4; ++mt) {
            int mb = m0 + wm * 64 + mt * 16 + quad * 4;
#pragma unroll
            for (int r = 0; r < 4; ++r)
                out[(size_t)(mb + r) * DD + n] = acc[mt][nt][r] + bv_;
        }
    }
}

// ---------------- flash attention: S^T layout, bf16, async dbuf staging ----------------
__global__ __launch_bounds__(256) void attn_mfma(const u16* __restrict__ Qb,
                                                 const u16* __restrict__ Kb,
                                                 const u16* __restrict__ Vb,
                                                 const int* __restrict__ mask,
                                                 const int* __restrict__ flags,
                                                 u16* __restrict__ C) {
    __shared__ u16 Qs[64 * 64];
    __shared__ u16 Ksb[2][64 * 64];
    __shared__ u16 Vtb[2][64 * 64];
    __shared__ u16 Pw[4][16 * 72];

    int blk = blockIdx.x;
    int qt = blk & 31;
    int bh = blk >> 5;
    int h = bh & 15;
    int b = bh >> 4;
    int q0 = qt * 64;

    const u16* Qg = Qb + ((size_t)bh * SS + q0) * DKK;  // 4096 shorts linear
    const u16* Kg = Kb + (size_t)bh * SS * DKK;
    const u16* Vg = Vb + (size_t)bh * DKK * SS;
    const int* flg = flags + (qt << 5);

    int t = threadIdx.x;
    int w = t >> 6;
    int lane = t & 63;
    int quad = lane >> 4;
    int l16 = lane & 15;

    // ---- prologue: async-stage Q tile + K/V tile 0 ----
#pragma unroll
    for (int i = 0; i < 2; ++i) {
        int c = t + i * 256;                         // 0..511
        gld16(Qg + c * 8, &Qs[c * 8]);
        gld16(Kg + (size_t)(c >> 3) * DKK + (c & 7) * 8, &Ksb[0][c * 8]);
        gld16(Vg + (size_t)(c >> 3) * SS + (c & 7) * 8, &Vtb[0][c * 8]);
    }
    __syncthreads();

    int qr = w * 16 + l16;
    frag_ab bq0 = *(const frag_ab*)&Qs[qr * 64 + quad * 8];
    frag_ab bq1 = *(const frag_ab*)&Qs[qr * 64 + 32 + quad * 8];

    frag_cd o[4];
#pragma unroll
    for (int dt = 0; dt < 4; ++dt) o[dt] = frag_cd{0.f, 0.f, 0.f, 0.f};
    float m_prev = -1e30f;
    float l_run = 0.f;

    for (int kt = 0; kt < 32; ++kt) {
        const u16* Ks = Ksb[kt & 1];
        const u16* Vt = Vtb[kt & 1];
        // ---- async prefetch next tile into other buffer (overlaps compute) ----
        if (kt < 31) {
            u16* Kn = Ksb[(kt + 1) & 1];
            u16* Vn = Vtb[(kt + 1) & 1];
#pragma unroll
            for (int i = 0; i < 2; ++i) {
                int c = t + i * 256;
                gld16(Kg + (size_t)((kt + 1) * 64 + (c >> 3)) * DKK + (c & 7) * 8, &Kn[c * 8]);
                gld16(Vg + (size_t)(c >> 3) * SS + (kt + 1) * 64 + (c & 7) * 8, &Vn[c * 8]);
            }
        }
        int anyzero = flg[kt];

        // ---- S^T = K_tile · Q^T : col=l16=q, row=quad*4+r=key ----
        float s[4][4];
#pragma unroll
        for (int nt = 0; nt < 4; ++nt) {
            int kr = nt * 16 + l16;
            frag_ab ak0 = *(const frag_ab*)&Ks[kr * 64 + quad * 8];
            frag_ab ak1 = *(const frag_ab*)&Ks[kr * 64 + 32 + quad * 8];
            frag_cd sf = frag_cd{0.f, 0.f, 0.f, 0.f};
            sf = __builtin_amdgcn_mfma_f32_16x16x32_bf16(ak0, bq0, sf, 0, 0, 0);
            sf = __builtin_amdgcn_mfma_f32_16x16x32_bf16(ak1, bq1, sf, 0, 0, 0);
#pragma unroll
            for (int r = 0; r < 4; ++r) s[nt][r] = sf[r];
        }

        if (anyzero) {
            int qg = q0 + w * 16 + l16;
#pragma unroll
            for (int nt = 0; nt < 4; ++nt)
#pragma unroll
                for (int r = 0; r < 4; ++r) {
                    int kg = kt * 64 + nt * 16 + quad * 4 + r;
                    if (mask[(size_t)qg * SS + kg] == 0) s[nt][r] = -1e9f;
                }
        }

        // ---- online softmax: per-lane scalar state ----
        float mc = s[0][0];
#pragma unroll
        for (int nt = 0; nt < 4; ++nt)
#pragma unroll
            for (int r = 0; r < 4; ++r) mc = fmaxf(mc, s[nt][r]);
        mc = fmaxf(mc, __shfl_xor(mc, 16));
        mc = fmaxf(mc, __shfl_xor(mc, 32));
        float mnew = fmaxf(m_prev, mc);
        float alpha = __expf(m_prev - mnew);

        float p[4][4];
        float ls = 0.f;
#pragma unroll
        for (int nt = 0; nt < 4; ++nt)
#pragma unroll
            for (int r = 0; r < 4; ++r) {
                p[nt][r] = __expf(s[nt][r] - mnew);
                ls += p[nt][r];
            }
        ls += __shfl_xor(ls, 16);
        ls += __shfl_xor(ls, 32);
        l_run = l_run * alpha + ls;
        m_prev = mnew;

#pragma unroll
        for (int dt = 0; dt < 4; ++dt)
#pragma unroll
            for (int r = 0; r < 4; ++r) o[dt][r] *= alpha;

        // ---- P^T store: Pw[q=l16][key] ----
#pragma unroll
        for (int nt = 0; nt < 4; ++nt) {
            ushort4 up;
            up.x = f2bf(p[nt][0]); up.y = f2bf(p[nt][1]);
            up.z = f2bf(p[nt][2]); up.w = f2bf(p[nt][3]);
            *(ushort4*)&Pw[w][l16 * 72 + nt * 16 + quad * 4] = up;
        }
        frag_ab bp0 = *(const frag_ab*)&Pw[w][l16 * 72 + quad * 8];
        frag_ab bp1 = *(const frag_ab*)&Pw[w][l16 * 72 + 32 + quad * 8];

        // ---- O^T += V^T · P^T ----
#pragma unroll
        for (int dt = 0; dt < 4; ++dt) {
            int dr = dt * 16 + l16;
            frag_ab av0 = *(const frag_ab*)&Vt[dr * 64 + quad * 8];
            frag_ab av1 = *(const frag_ab*)&Vt[dr * 64 + 32 + quad * 8];
            o[dt] = __builtin_amdgcn_mfma_f32_16x16x32_bf16(av0, bp0, o[dt], 0, 0, 0);
            o[dt] = __builtin_amdgcn_mfma_f32_16x16x32_bf16(av1, bp1, o[dt], 0, 0, 0);
        }
        __syncthreads();  // drains prefetch (vmcnt 0) + LDS reads of current bufs
    }

    // ---- epilogue: O^T (col=l16=q, row=quad*4+r=d) -> bf16 [B,S,D] ----
    float inv = 1.f / l_run;
    int qg = q0 + w * 16 + l16;
    u16* Crow = C + ((size_t)b * SS + qg) * DD + h * 64;
#pragma unroll
    for (int dt = 0; dt < 4; ++dt) {
        ushort4 u;
        u.x = f2bf(o[dt][0] * inv);
        u.y = f2bf(o[dt][1] * inv);
        u.z = f2bf(o[dt][2] * inv);
        u.w = f2bf(o[dt][3] * inv);
        *(ushort4*)&Crow[dt * 16 + quad * 4] = u;
    }
}

extern "C" void kernel_launch(void* const* d_in, const int* in_sizes, int n_in,
                              void* d_out, int out_size, void* d_ws, size_t ws_size,
                              hipStream_t stream) {
    const float* q = (const float*)d_in[0];
    const float* k = (const float*)d_in[1];
    const float* v = (const float*)d_in[2];
    const int* mask = (const int*)d_in[3];
    const float* Wq = (const float*)d_in[4];
    const float* bq = (const float*)d_in[5];
    const float* Wk = (const float*)d_in[6];
    const float* bk = (const float*)d_in[7];
    const float* Wv = (const float*)d_in[8];
    const float* bv = (const float*)d_in[9];
    const float* Wo = (const float*)d_in[10];
    const float* bo = (const float*)d_in[11];
    float* out = (float*)d_out;

    const size_t MB = 1024u * 1024u;
    char* ws = (char*)d_ws;
    u16* qb = (u16*)(ws + 0 * MB);     // 8 MB (reused as Cw after qkv_gemm)
    u16* kb = (u16*)(ws + 8 * MB);     // 8 MB
    u16* vb = (u16*)(ws + 16 * MB);    // 8 MB
    u16* Wqb = (u16*)(ws + 24 * MB);   // 2 MB
    u16* Wkb = (u16*)(ws + 26 * MB);
    u16* Wvb = (u16*)(ws + 28 * MB);
    u16* Wob = (u16*)(ws + 30 * MB);
    u16* Qb = (u16*)(ws + 32 * MB);    // 8 MB
    u16* Kb = (u16*)(ws + 40 * MB);
    u16* Vb = (u16*)(ws + 48 * MB);
    int* flags = (int*)(ws + 56 * MB); // 4 KB
    u16* Cw = qb;                       // reuse

    prep<<<9216, 256, 0, stream>>>(q, k, v, Wq, Wk, Wv, Wo,
                                   qb, kb, vb, Wqb, Wkb, Wvb, Wob, mask, flags);

    dim3 grid(DD / 128, (BB * SS) / 128, 3);  // 8 x 32 x 3 = 768 blocks
    qkv_gemm<<<grid, 256, 0, stream>>>(qb, kb, vb, Wqb, Wkb, Wvb,
                                       bq, bk, bv, Qb, Kb, Vb);

    attn_mfma<<<BB * HH * (SS / 64), 256, 0, stream>>>(Qb, Kb, Vb, mask, flags, Cw);

    out_gemm<<<dim3(DD / 128, (BB * SS) / 128), 256, 0, stream>>>(Cw, Wob, bo, out);
}

// Round 8
// 291.220 us; speedup vs baseline: 27.6820x; 1.0260x over previous
//
#include <hip/hip_runtime.h>
#include <hip/hip_bf16.h>

#define BB 2
#define SS 2048
#define DD 1024
#define HH 16
#define DKK 64
// M = BB*SS = 4096, N = K = DD = 1024

typedef __hip_bfloat16 bf16;
typedef unsigned short u16;
using frag_ab = __attribute__((ext_vector_type(8))) short;  // 8 bf16 (4 VGPRs)
using frag_cd = __attribute__((ext_vector_type(4))) float;  // 4 fp32

__device__ inline u16 f2bf(float f) {
    bf16 h = __float2bfloat16(f);
    return *reinterpret_cast<u16*>(&h);
}

// async global->LDS, 16B per lane (lds dest = wave-uniform base + lane*16)
__device__ inline void gld16(const void* g, void* l) {
    __builtin_amdgcn_global_load_lds((const __attribute__((address_space(1))) void*)g,
                                     (__attribute__((address_space(3))) void*)l,
                                     16, 0, 0);
}

// ---------------- prep: fp32->bf16 converts + mask tile flags ----------------
__global__ __launch_bounds__(256) void prep(
    const float* __restrict__ q, const float* __restrict__ k, const float* __restrict__ v,
    const float* __restrict__ Wq, const float* __restrict__ Wk,
    const float* __restrict__ Wv, const float* __restrict__ Wo,
    u16* __restrict__ qb, u16* __restrict__ kb, u16* __restrict__ vb,
    u16* __restrict__ Wqb, u16* __restrict__ Wkb, u16* __restrict__ Wvb, u16* __restrict__ Wob,
    const int* __restrict__ mask, int* __restrict__ flags) {
    int bid = blockIdx.x;
    int t = threadIdx.x;
    if (bid < 8192) {
        const float* src;
        u16* dst;
        int local;
        if (bid < 6144) {
            int ts = bid >> 11;
            local = bid & 2047;
            src = ts == 0 ? q : (ts == 1 ? k : v);
            dst = ts == 0 ? qb : (ts == 1 ? kb : vb);
        } else {
            int wsel = (bid - 6144) >> 9;
            local = (bid - 6144) & 511;
            src = wsel == 0 ? Wq : (wsel == 1 ? Wk : (wsel == 2 ? Wv : Wo));
            dst = wsel == 0 ? Wqb : (wsel == 1 ? Wkb : (wsel == 2 ? Wvb : Wob));
        }
        size_t base = (size_t)local * 2048 + t * 8;
        float4 a = *(const float4*)&src[base];
        float4 b = *(const float4*)&src[base + 4];
        ushort4 u0, u1;
        u0.x = f2bf(a.x); u0.y = f2bf(a.y); u0.z = f2bf(a.z); u0.w = f2bf(a.w);
        u1.x = f2bf(b.x); u1.y = f2bf(b.y); u1.z = f2bf(b.z); u1.w = f2bf(b.w);
        *(ushort4*)&dst[base] = u0;
        *(ushort4*)&dst[base + 4] = u1;
    } else {
        int tile = bid - 8192;
        int qt = tile >> 5, kt = tile & 31;
        __shared__ int f;
        if (t == 0) f = 0;
        __syncthreads();
        int qq = qt * 64 + (t >> 2);
        const int4* row = (const int4*)(mask + (size_t)qq * SS + kt * 64 + (t & 3) * 16);
        int anyz = 0;
#pragma unroll
        for (int i = 0; i < 4; ++i) {
            int4 m4 = row[i];
            anyz |= (m4.x == 0) | (m4.y == 0) | (m4.z == 0) | (m4.w == 0);
        }
        if (anyz) f = 1;
        __syncthreads();
        if (t == 0) flags[tile] = f;
    }
}

// ---------------- fused QKV GEMM (bf16 in, bf16 out) ----------------
__global__ __launch_bounds__(256) void qkv_gemm(
    const u16* __restrict__ Aq, const u16* __restrict__ Ak, const u16* __restrict__ Av,
    const u16* __restrict__ Wq, const u16* __restrict__ Wk, const u16* __restrict__ Wv,
    const float* __restrict__ bq, const float* __restrict__ bk, const float* __restrict__ bv,
    u16* __restrict__ Qo, u16* __restrict__ Ko, u16* __restrict__ Vo) {
    __shared__ u16 As[128 * 32];
    __shared__ u16 Bs[128 * 32];

    int z = blockIdx.z;
    const u16* A = z == 0 ? Aq : (z == 1 ? Ak : Av);
    const u16* W = z == 0 ? Wq : (z == 1 ? Wk : Wv);
    const float* bias = z == 0 ? bq : (z == 1 ? bk : bv);
    u16* out = z == 0 ? Qo : (z == 1 ? Ko : Vo);

    int t = threadIdx.x;
    int m0 = blockIdx.y * 128;
    int n0 = blockIdx.x * 128;
    int w = t >> 6, lane = t & 63;
    int quad = lane >> 4, l16 = lane & 15;
    int wm = w >> 1, wn = w & 1;

    const u16* Ab = A + (size_t)m0 * DD;
    const u16* Wb = W + (size_t)n0 * DD;

    frag_cd acc[4][4];
#pragma unroll
    for (int mt = 0; mt < 4; ++mt)
#pragma unroll
        for (int nt = 0; nt < 4; ++nt) acc[mt][nt] = frag_cd{0.f, 0.f, 0.f, 0.f};

    for (int k0 = 0; k0 < DD; k0 += 32) {
        if (k0) __syncthreads();
#pragma unroll
        for (int i = 0; i < 2; ++i) {
            int c = t + i * 256;
            int row = c >> 2, kc = (c & 3) * 8;
            gld16(Ab + (size_t)row * DD + k0 + kc, &As[c * 8]);
            gld16(Wb + (size_t)row * DD + k0 + kc, &Bs[c * 8]);
        }
        __syncthreads();

        frag_ab af[4], bfr[4];
#pragma unroll
        for (int mt = 0; mt < 4; ++mt)
            af[mt] = *(const frag_ab*)&As[(wm * 64 + mt * 16 + l16) * 32 + quad * 8];
#pragma unroll
        for (int nt = 0; nt < 4; ++nt)
            bfr[nt] = *(const frag_ab*)&Bs[(wn * 64 + nt * 16 + l16) * 32 + quad * 8];
#pragma unroll
        for (int mt = 0; mt < 4; ++mt)
#pragma unroll
            for (int nt = 0; nt < 4; ++nt)
                acc[mt][nt] = __builtin_amdgcn_mfma_f32_16x16x32_bf16(
                    af[mt], bfr[nt], acc[mt][nt], 0, 0, 0);
    }

    float scale = z == 0 ? 0.125f : 1.0f;
#pragma unroll
    for (int nt = 0; nt < 4; ++nt) {
        int n = n0 + wn * 64 + nt * 16 + l16;
        float bv_ = bias[n];
        int h_ = n >> 6, d_ = n & 63;
#pragma unroll
        for (int mt = 0; mt < 4; ++mt) {
            int mb = m0 + wm * 64 + mt * 16 + quad * 4;
            int b_ = mb >> 11, s_ = mb & 2047;
            if (z == 2) {
                ushort4 u;
                u.x = f2bf(acc[mt][nt][0] + bv_);
                u.y = f2bf(acc[mt][nt][1] + bv_);
                u.z = f2bf(acc[mt][nt][2] + bv_);
                u.w = f2bf(acc[mt][nt][3] + bv_);
                *(ushort4*)&out[((size_t)(b_ * HH + h_) * DKK + d_) * SS + s_] = u;
            } else {
#pragma unroll
                for (int r = 0; r < 4; ++r)
                    out[((size_t)(b_ * HH + h_) * SS + s_ + r) * DKK + d_] =
                        f2bf((acc[mt][nt][r] + bv_) * scale);
            }
        }
    }
}

// ---------------- output GEMM: fp32 out = Cw(bf16) @ Wo^T + bo ----------------
__global__ __launch_bounds__(256) void out_gemm(const u16* __restrict__ A,
                                                const u16* __restrict__ W,
                                                const float* __restrict__ bias,
                                                float* __restrict__ out) {
    __shared__ u16 As[128 * 32];
    __shared__ u16 Bs[128 * 32];

    int t = threadIdx.x;
    int m0 = blockIdx.y * 128;
    int n0 = blockIdx.x * 128;
    int w = t >> 6, lane = t & 63;
    int quad = lane >> 4, l16 = lane & 15;
    int wm = w >> 1, wn = w & 1;

    const u16* Ab = A + (size_t)m0 * DD;
    const u16* Wb = W + (size_t)n0 * DD;

    frag_cd acc[4][4];
#pragma unroll
    for (int mt = 0; mt < 4; ++mt)
#pragma unroll
        for (int nt = 0; nt < 4; ++nt) acc[mt][nt] = frag_cd{0.f, 0.f, 0.f, 0.f};

    for (int k0 = 0; k0 < DD; k0 += 32) {
        if (k0) __syncthreads();
#pragma unroll
        for (int i = 0; i < 2; ++i) {
            int c = t + i * 256;
            int row = c >> 2, kc = (c & 3) * 8;
            gld16(Ab + (size_t)row * DD + k0 + kc, &As[c * 8]);
            gld16(Wb + (size_t)row * DD + k0 + kc, &Bs[c * 8]);
        }
        __syncthreads();

        frag_ab af[4], bfr[4];
#pragma unroll
        for (int mt = 0; mt < 4; ++mt)
            af[mt] = *(const frag_ab*)&As[(wm * 64 + mt * 16 + l16) * 32 + quad * 8];
#pragma unroll
        for (int nt = 0; nt < 4; ++nt)
            bfr[nt] = *(const frag_ab*)&Bs[(wn * 64 + nt * 16 + l16) * 32 + quad * 8];
#pragma unroll
        for (int mt = 0; mt < 4; ++mt)
#pragma unroll
            for (int nt = 0; nt < 4; ++nt)
                acc[mt][nt] = __builtin_amdgcn_mfma_f32_16x16x32_bf16(
                    af[mt], bfr[nt], acc[mt][nt], 0, 0, 0);
    }

#pragma unroll
    for (int nt = 0; nt < 4; ++nt) {
        int n = n0 + wn * 64 + nt * 16 + l16;
        float bv_ = bias[n];
#pragma unroll
        for (int mt = 0; mt < 4; ++mt) {
            int mb = m0 + wm * 64 + mt * 16 + quad * 4;
#pragma unroll
            for (int r = 0; r < 4; ++r)
                out[(size_t)(mb + r) * DD + n] = acc[mt][nt][r] + bv_;
        }
    }
}

// ---------------- flash attention: 128-q tile, 2 softmax chains per wave ----------------
// Grid: B*H*(S/128) = 512 blocks, 256 threads. Wave w owns q columns
// {q0 + g*64 + w*16 + l16 : g=0,1}. S^T = K·Q^T (col=l16=q, row=quad*4+r=key).
// Single-buffer K/V staging with register prefetch (R6-proven).
__global__ __launch_bounds__(256) void attn_mfma(const u16* __restrict__ Qb,
                                                 const u16* __restrict__ Kb,
                                                 const u16* __restrict__ Vb,
                                                 const int* __restrict__ mask,
                                                 const int* __restrict__ flags,
                                                 u16* __restrict__ C) {
    __shared__ u16 Ks[64 * 64];      // [key][d]
    __shared__ u16 Vt[64 * 64];      // [d][key]
    __shared__ u16 Pw[4][2][16 * 72];// per-wave, per-group P^T [q][key]

    int blk = blockIdx.x;
    int Qt = blk & 15;          // q-128-tile index
    int bh = blk >> 4;
    int h = bh & 15;
    int b = bh >> 4;
    int q0 = Qt * 128;

    const u16* Kg = Kb + (size_t)bh * SS * DKK;
    const u16* Vg = Vb + (size_t)bh * DKK * SS;

    int t = threadIdx.x;
    int w = t >> 6;
    int lane = t & 63;
    int quad = lane >> 4;
    int l16 = lane & 15;

    // ---- Q B-frags direct from global (one-time, per group) ----
    frag_ab bq[2][2];
#pragma unroll
    for (int g = 0; g < 2; ++g) {
        const u16* Qr = Qb + ((size_t)bh * SS + q0 + g * 64 + w * 16 + l16) * DKK;
        bq[g][0] = *(const frag_ab*)&Qr[quad * 8];
        bq[g][1] = *(const frag_ab*)&Qr[32 + quad * 8];
    }

    frag_cd o[2][4];
#pragma unroll
    for (int g = 0; g < 2; ++g)
#pragma unroll
        for (int dt = 0; dt < 4; ++dt) o[g][dt] = frag_cd{0.f, 0.f, 0.f, 0.f};
    float m_prev[2] = {-1e30f, -1e30f};
    float l_run[2] = {0.f, 0.f};

    // V staging geometry
    int vd = t >> 2;
    int vc = (t & 3) * 16;

    // ---- register prefetch of tile 0 ----
    int4 kr0, kr1, vr0, vr1;
    {
        const int4* Kt = (const int4*)Kg;
        kr0 = Kt[2 * t]; kr1 = Kt[2 * t + 1];
        const int4* Vr = (const int4*)(Vg + (size_t)vd * SS + vc);
        vr0 = Vr[0]; vr1 = Vr[1];
    }

    for (int kt = 0; kt < 32; ++kt) {
        if (kt) __syncthreads();  // (A) prior tile's frag reads complete
        ((int4*)Ks)[2 * t] = kr0;
        ((int4*)Ks)[2 * t + 1] = kr1;
        *(int4*)&Vt[vd * 64 + vc] = vr0;
        *(int4*)&Vt[vd * 64 + vc + 8] = vr1;
        if (kt < 31) {
            const int4* Kt = (const int4*)(Kg + (size_t)(kt + 1) * 4096);
            kr0 = Kt[2 * t]; kr1 = Kt[2 * t + 1];
            const int4* Vr = (const int4*)(Vg + (size_t)vd * SS + (kt + 1) * 64 + vc);
            vr0 = Vr[0]; vr1 = Vr[1];
        }
        int az[2];
        az[0] = flags[(Qt * 2) * 32 + kt];
        az[1] = flags[(Qt * 2 + 1) * 32 + kt];
        __syncthreads();  // (B) staged tile visible

#pragma unroll
        for (int g = 0; g < 2; ++g) {
            // ---- S^T = K_tile · Q^T ----
            float s[4][4];
#pragma unroll
            for (int nt = 0; nt < 4; ++nt) {
                int kr = nt * 16 + l16;
                frag_ab ak0 = *(const frag_ab*)&Ks[kr * 64 + quad * 8];
                frag_ab ak1 = *(const frag_ab*)&Ks[kr * 64 + 32 + quad * 8];
                frag_cd sf = frag_cd{0.f, 0.f, 0.f, 0.f};
                sf = __builtin_amdgcn_mfma_f32_16x16x32_bf16(ak0, bq[g][0], sf, 0, 0, 0);
                sf = __builtin_amdgcn_mfma_f32_16x16x32_bf16(ak1, bq[g][1], sf, 0, 0, 0);
#pragma unroll
                for (int r = 0; r < 4; ++r) s[nt][r] = sf[r];
            }

            if (az[g]) {
                int qg = q0 + g * 64 + w * 16 + l16;
#pragma unroll
                for (int nt = 0; nt < 4; ++nt)
#pragma unroll
                    for (int r = 0; r < 4; ++r) {
                        int kg = kt * 64 + nt * 16 + quad * 4 + r;
                        if (mask[(size_t)qg * SS + kg] == 0) s[nt][r] = -1e9f;
                    }
            }

            // ---- online softmax (per-lane scalar state) ----
            float mc = s[0][0];
#pragma unroll
            for (int nt = 0; nt < 4; ++nt)
#pragma unroll
                for (int r = 0; r < 4; ++r) mc = fmaxf(mc, s[nt][r]);
            mc = fmaxf(mc, __shfl_xor(mc, 16));
            mc = fmaxf(mc, __shfl_xor(mc, 32));
            float mnew = fmaxf(m_prev[g], mc);
            float alpha = __expf(m_prev[g] - mnew);

            float p[4][4];
            float ls = 0.f;
#pragma unroll
            for (int nt = 0; nt < 4; ++nt)
#pragma unroll
                for (int r = 0; r < 4; ++r) {
                    p[nt][r] = __expf(s[nt][r] - mnew);
                    ls += p[nt][r];
                }
            ls += __shfl_xor(ls, 16);
            ls += __shfl_xor(ls, 32);
            l_run[g] = l_run[g] * alpha + ls;
            m_prev[g] = mnew;

#pragma unroll
            for (int dt = 0; dt < 4; ++dt)
#pragma unroll
                for (int r = 0; r < 4; ++r) o[g][dt][r] *= alpha;

            // ---- P^T round-trip ----
#pragma unroll
            for (int nt = 0; nt < 4; ++nt) {
                ushort4 up;
                up.x = f2bf(p[nt][0]); up.y = f2bf(p[nt][1]);
                up.z = f2bf(p[nt][2]); up.w = f2bf(p[nt][3]);
                *(ushort4*)&Pw[w][g][l16 * 72 + nt * 16 + quad * 4] = up;
            }
            frag_ab bp0 = *(const frag_ab*)&Pw[w][g][l16 * 72 + quad * 8];
            frag_ab bp1 = *(const frag_ab*)&Pw[w][g][l16 * 72 + 32 + quad * 8];

            // ---- O^T += V^T · P^T ----
#pragma unroll
            for (int dt = 0; dt < 4; ++dt) {
                int dr = dt * 16 + l16;
                frag_ab av0 = *(const frag_ab*)&Vt[dr * 64 + quad * 8];
                frag_ab av1 = *(const frag_ab*)&Vt[dr * 64 + 32 + quad * 8];
                o[g][dt] = __builtin_amdgcn_mfma_f32_16x16x32_bf16(av0, bp0, o[g][dt], 0, 0, 0);
                o[g][dt] = __builtin_amdgcn_mfma_f32_16x16x32_bf16(av1, bp1, o[g][dt], 0, 0, 0);
            }
        }
    }

    // ---- epilogue: bf16 [B,S,D] ----
#pragma unroll
    for (int g = 0; g < 2; ++g) {
        float inv = 1.f / l_run[g];
        int qg = q0 + g * 64 + w * 16 + l16;
        u16* Crow = C + ((size_t)b * SS + qg) * DD + h * 64;
#pragma unroll
        for (int dt = 0; dt < 4; ++dt) {
            ushort4 u;
            u.x = f2bf(o[g][dt][0] * inv);
            u.y = f2bf(o[g][dt][1] * inv);
            u.z = f2bf(o[g][dt][2] * inv);
            u.w = f2bf(o[g][dt][3] * inv);
            *(ushort4*)&Crow[dt * 16 + quad * 4] = u;
        }
    }
}

extern "C" void kernel_launch(void* const* d_in, const int* in_sizes, int n_in,
                              void* d_out, int out_size, void* d_ws, size_t ws_size,
                              hipStream_t stream) {
    const float* q = (const float*)d_in[0];
    const float* k = (const float*)d_in[1];
    const float* v = (const float*)d_in[2];
    const int* mask = (const int*)d_in[3];
    const float* Wq = (const float*)d_in[4];
    const float* bq = (const float*)d_in[5];
    const float* Wk = (const float*)d_in[6];
    const float* bk = (const float*)d_in[7];
    const float* Wv = (const float*)d_in[8];
    const float* bv = (const float*)d_in[9];
    const float* Wo = (const float*)d_in[10];
    const float* bo = (const float*)d_in[11];
    float* out = (float*)d_out;

    const size_t MB = 1024u * 1024u;
    char* ws = (char*)d_ws;
    u16* qb = (u16*)(ws + 0 * MB);     // 8 MB (reused as Cw after qkv_gemm)
    u16* kb = (u16*)(ws + 8 * MB);
    u16* vb = (u16*)(ws + 16 * MB);
    u16* Wqb = (u16*)(ws + 24 * MB);
    u16* Wkb = (u16*)(ws + 26 * MB);
    u16* Wvb = (u16*)(ws + 28 * MB);
    u16* Wob = (u16*)(ws + 30 * MB);
    u16* Qb = (u16*)(ws + 32 * MB);
    u16* Kb = (u16*)(ws + 40 * MB);
    u16* Vb = (u16*)(ws + 48 * MB);
    int* flags = (int*)(ws + 56 * MB);
    u16* Cw = qb;

    prep<<<9216, 256, 0, stream>>>(q, k, v, Wq, Wk, Wv, Wo,
                                   qb, kb, vb, Wqb, Wkb, Wvb, Wob, mask, flags);

    dim3 grid(DD / 128, (BB * SS) / 128, 3);
    qkv_gemm<<<grid, 256, 0, stream>>>(qb, kb, vb, Wqb, Wkb, Wvb,
                                       bq, bk, bv, Qb, Kb, Vb);

    attn_mfma<<<BB * HH * (SS / 128), 256, 0, stream>>>(Qb, Kb, Vb, mask, flags, Cw);

    out_gemm<<<dim3(DD / 128, (BB * SS) / 128), 256, 0, stream>>>(Cw, Wob, bo, out);
}